// Round 1
// baseline (3337.228 us; speedup 1.0000x reference)
//
#include <hip/hip_runtime.h>
#include <hip/hip_bf16.h>
#include <cstddef>

#define D_MODEL 1024
#define D_STATE 16
#define D_CONV 4
#define DT_RANK 64
#define D_INNER 2048
#define BB 2
#define LL 2048
#define TT (BB * LL)   // 4096 tokens

// ---------------------------------------------------------------------------
// LayerNorm: one block per token, 256 threads, float4 per thread (1024 elems)
// ---------------------------------------------------------------------------
__global__ __launch_bounds__(256) void layernorm_kernel(
    const float* __restrict__ x, const float* __restrict__ w,
    const float* __restrict__ b, float* __restrict__ xn) {
  int t = blockIdx.x;
  int tid = threadIdx.x;
  const float4* xr = reinterpret_cast<const float4*>(x + (size_t)t * D_MODEL);
  float4 xv = xr[tid];
  float s = xv.x + xv.y + xv.z + xv.w;
  float sq = xv.x * xv.x + xv.y * xv.y + xv.z * xv.z + xv.w * xv.w;
  // wave reduce (64 lanes)
  for (int off = 32; off >= 1; off >>= 1) {
    s += __shfl_down(s, off);
    sq += __shfl_down(sq, off);
  }
  __shared__ float red[8];
  int wave = tid >> 6;
  if ((tid & 63) == 0) { red[wave * 2] = s; red[wave * 2 + 1] = sq; }
  __syncthreads();
  if (tid == 0) {
    float S = 0.f, Q = 0.f;
    for (int i = 0; i < 4; ++i) { S += red[2 * i]; Q += red[2 * i + 1]; }
    float mean = S * (1.f / D_MODEL);
    float var = Q * (1.f / D_MODEL) - mean * mean;
    red[0] = mean;
    red[1] = rsqrtf(var + 1e-5f);
  }
  __syncthreads();
  float mean = red[0], inv = red[1];
  const float4* wr = reinterpret_cast<const float4*>(w);
  const float4* br = reinterpret_cast<const float4*>(b);
  float4 wv = wr[tid], bv = br[tid];
  float4 o;
  o.x = (xv.x - mean) * inv * wv.x + bv.x;
  o.y = (xv.y - mean) * inv * wv.y + bv.y;
  o.z = (xv.z - mean) * inv * wv.z + bv.z;
  o.w = (xv.w - mean) * inv * wv.w + bv.w;
  reinterpret_cast<float4*>(xn + (size_t)t * D_MODEL)[tid] = o;
}

// ---------------------------------------------------------------------------
// Generic fp32 NT GEMM: C[M,N] = A[M,K] * B[N,K]^T  (+ epilogue)
// EPI 0: none; 1: softplus(v + bias[col]); 2: v + resid[row*ldr+col]
// ---------------------------------------------------------------------------
template <int EPI>
__global__ __launch_bounds__(256) void gemm_nt_kernel(
    const float* __restrict__ A, int lda, const float* __restrict__ B, int ldb,
    float* __restrict__ C, int ldc, int M, int N, int K,
    const float* __restrict__ bias, const float* __restrict__ resid, int ldr) {
  constexpr int BM = 64, BN = 64, BK = 16, TM = 4, TN = 4;
  __shared__ float As[BK][BM + 1];
  __shared__ float Bs[BK][BN + 1];
  int tid = threadIdx.x;
  int tx = tid & 15;        // 0..15 -> col group
  int ty = tid >> 4;        // 0..15 -> row group
  int row0 = blockIdx.y * BM;
  int col0 = blockIdx.x * BN;
  int lk = tid & (BK - 1);  // 0..15
  int lr = tid / BK;        // 0..15
  float acc[TM][TN] = {};
  for (int k0 = 0; k0 < K; k0 += BK) {
#pragma unroll
    for (int i = 0; i < 4; ++i) {
      int r = lr + 16 * i;
      int gr = row0 + r;
      float v = 0.f;
      if (gr < M) v = A[(size_t)gr * lda + k0 + lk];
      As[lk][r] = v;
    }
#pragma unroll
    for (int i = 0; i < 4; ++i) {
      int r = lr + 16 * i;
      int gc = col0 + r;
      float v = 0.f;
      if (gc < N) v = B[(size_t)gc * ldb + k0 + lk];
      Bs[lk][r] = v;
    }
    __syncthreads();
#pragma unroll
    for (int k = 0; k < BK; ++k) {
      float a[TM], bv[TN];
#pragma unroll
      for (int i = 0; i < TM; ++i) a[i] = As[k][ty * TM + i];
#pragma unroll
      for (int j = 0; j < TN; ++j) bv[j] = Bs[k][tx * TN + j];
#pragma unroll
      for (int i = 0; i < TM; ++i)
#pragma unroll
        for (int j = 0; j < TN; ++j) acc[i][j] += a[i] * bv[j];
    }
    __syncthreads();
  }
#pragma unroll
  for (int i = 0; i < TM; ++i) {
    int gr = row0 + ty * TM + i;
    if (gr >= M) continue;
#pragma unroll
    for (int j = 0; j < TN; ++j) {
      int gc = col0 + tx * TN + j;
      if (gc >= N) continue;
      float v = acc[i][j];
      if (EPI == 1) {
        float xv = v + bias[gc];
        v = fmaxf(xv, 0.f) + log1pf(expf(-fabsf(xv)));
      }
      if (EPI == 2) v += resid[(size_t)gr * ldr + gc];
      C[(size_t)gr * ldc + gc] = v;
    }
  }
}

// ---------------------------------------------------------------------------
// Depthwise causal conv (width 4) + SiLU. One thread per (t,d) element.
// ---------------------------------------------------------------------------
__global__ __launch_bounds__(256) void conv_silu_kernel(
    const float* __restrict__ u, const float* __restrict__ cw,
    const float* __restrict__ cb, float* __restrict__ uc) {
  size_t idx = (size_t)blockIdx.x * 256 + threadIdx.x;
  if (idx >= (size_t)TT * D_INNER) return;
  int d = (int)(idx & (D_INNER - 1));
  int t = (int)(idx >> 11);
  int l = t & (LL - 1);
  float acc = cb[d];
#pragma unroll
  for (int k = 0; k < D_CONV; ++k) {
    int ll = l - (D_CONV - 1) + k;
    if (ll >= 0) acc += u[idx - (size_t)(D_CONV - 1 - k) * D_INNER] * cw[d * D_CONV + k];
  }
  uc[idx] = acc / (1.f + expf(-acc));  // SiLU
}

// ---------------------------------------------------------------------------
// Selective scan. Block = 256 threads = 16 channel-groups x 16 state lanes.
// grid = (B*D_INNER)/16 = 256 blocks. Fuses +u*D, *silu(z) into the write.
// ---------------------------------------------------------------------------
__global__ __launch_bounds__(256) void scan_kernel(
    const float* __restrict__ delta, const float* __restrict__ uc,
    const float* __restrict__ xd,    // x_dbl: (T, 96); B at +64, C at +80
    const float* __restrict__ z, const float* __restrict__ A_log,
    const float* __restrict__ Dv, float* __restrict__ y) {
  int tid = threadIdx.x;
  int n = tid & 15;
  int g = tid >> 4;
  int chan = blockIdx.x * 16 + g;  // chan = b*D_INNER + d
  int b = chan >> 11;
  int d = chan & (D_INNER - 1);
  float Acoef = -expf(A_log[d * D_STATE + n]);
  float Dd = Dv[d];
  float h = 0.f;
  size_t tbase = (size_t)b * LL;
  for (int l = 0; l < LL; ++l) {
    size_t t = tbase + l;
    float dl = delta[t * D_INNER + d];
    float ul = uc[t * D_INNER + d];
    float bn = xd[t * 96 + 64 + n];
    float cn = xd[t * 96 + 80 + n];
    float a = __expf(dl * Acoef);
    h = a * h + dl * bn * ul;
    float p = h * cn;
    p += __shfl_xor(p, 1);
    p += __shfl_xor(p, 2);
    p += __shfl_xor(p, 4);
    p += __shfl_xor(p, 8);
    if (n == 0) {
      float zv = z[t * D_INNER + d];
      float sz = zv / (1.f + expf(-zv));
      y[t * D_INNER + d] = (p + ul * Dd) * sz;
    }
  }
}

// ---------------------------------------------------------------------------
extern "C" void kernel_launch(void* const* d_in, const int* in_sizes, int n_in,
                              void* d_out, int out_size, void* d_ws, size_t ws_size,
                              hipStream_t stream) {
  const float* x         = (const float*)d_in[0];
  const float* ln_w      = (const float*)d_in[1];
  const float* ln_b      = (const float*)d_in[2];
  const float* in_proj_w = (const float*)d_in[3];
  const float* conv_w    = (const float*)d_in[4];
  const float* conv_b    = (const float*)d_in[5];
  const float* x_proj_w  = (const float*)d_in[6];
  const float* dt_proj_w = (const float*)d_in[7];
  const float* dt_proj_b = (const float*)d_in[8];
  const float* A_log     = (const float*)d_in[9];
  const float* Dvec      = (const float*)d_in[10];
  const float* out_proj_w= (const float*)d_in[11];
  float* out = (float*)d_out;

  float* ws = (float*)d_ws;
  float* xn    = ws;                       // T*1024
  float* u     = xn + (size_t)TT * D_MODEL;       // T*2048 (later reused as y)
  float* z     = u + (size_t)TT * D_INNER;        // T*2048
  float* uc    = z + (size_t)TT * D_INNER;        // T*2048
  float* xd    = uc + (size_t)TT * D_INNER;       // T*96
  float* delta = xd + (size_t)TT * 96;            // T*2048

  // 1. LayerNorm
  layernorm_kernel<<<TT, 256, 0, stream>>>(x, ln_w, ln_b, xn);

  // 2. in_proj -> u, z   (two N=2048 GEMMs over the split weight)
  gemm_nt_kernel<0><<<dim3(D_INNER / 64, TT / 64), 256, 0, stream>>>(
      xn, D_MODEL, in_proj_w, D_MODEL, u, D_INNER, TT, D_INNER, D_MODEL,
      nullptr, nullptr, 0);
  gemm_nt_kernel<0><<<dim3(D_INNER / 64, TT / 64), 256, 0, stream>>>(
      xn, D_MODEL, in_proj_w + (size_t)D_INNER * D_MODEL, D_MODEL, z, D_INNER,
      TT, D_INNER, D_MODEL, nullptr, nullptr, 0);

  // 3. causal depthwise conv + SiLU
  conv_silu_kernel<<<(TT * D_INNER) / 256, 256, 0, stream>>>(u, conv_w, conv_b, uc);

  // 4. x_proj -> x_dbl (N=96)
  gemm_nt_kernel<0><<<dim3(2, TT / 64), 256, 0, stream>>>(
      uc, D_INNER, x_proj_w, D_INNER, xd, 96, TT, 96, D_INNER,
      nullptr, nullptr, 0);

  // 5. dt_proj + softplus -> delta
  gemm_nt_kernel<1><<<dim3(D_INNER / 64, TT / 64), 256, 0, stream>>>(
      xd, 96, dt_proj_w, DT_RANK, delta, D_INNER, TT, D_INNER, DT_RANK,
      dt_proj_b, nullptr, 0);

  // 6. selective scan + gate (writes y into the u buffer)
  scan_kernel<<<(BB * D_INNER) / 16, 256, 0, stream>>>(
      delta, uc, xd, z, A_log, Dvec, u);

  // 7. out_proj + residual
  gemm_nt_kernel<2><<<dim3(D_MODEL / 64, TT / 64), 256, 0, stream>>>(
      u, D_INNER, out_proj_w, D_INNER, out, D_MODEL, TT, D_MODEL, D_INNER,
      nullptr, x, D_MODEL);
}

// Round 2
// 2044.210 us; speedup vs baseline: 1.6325x; 1.6325x over previous
//
#include <hip/hip_runtime.h>
#include <hip/hip_bf16.h>
#include <cstddef>

#define D_MODEL 1024
#define D_STATE 16
#define D_CONV 4
#define DT_RANK 64
#define D_INNER 2048
#define BB 2
#define LL 2048
#define TT (BB * LL)   // 4096 tokens
#define NSEG 64
#define SEGLEN (LL / NSEG)  // 32
#define NCHAN (BB * D_INNER)  // 4096

// ---------------------------------------------------------------------------
// LayerNorm: one block per token, 256 threads, float4 per thread (1024 elems)
// ---------------------------------------------------------------------------
__global__ __launch_bounds__(256) void layernorm_kernel(
    const float* __restrict__ x, const float* __restrict__ w,
    const float* __restrict__ b, float* __restrict__ xn) {
  int t = blockIdx.x;
  int tid = threadIdx.x;
  const float4* xr = reinterpret_cast<const float4*>(x + (size_t)t * D_MODEL);
  float4 xv = xr[tid];
  float s = xv.x + xv.y + xv.z + xv.w;
  float sq = xv.x * xv.x + xv.y * xv.y + xv.z * xv.z + xv.w * xv.w;
  for (int off = 32; off >= 1; off >>= 1) {
    s += __shfl_down(s, off);
    sq += __shfl_down(sq, off);
  }
  __shared__ float red[8];
  int wave = tid >> 6;
  if ((tid & 63) == 0) { red[wave * 2] = s; red[wave * 2 + 1] = sq; }
  __syncthreads();
  if (tid == 0) {
    float S = 0.f, Q = 0.f;
    for (int i = 0; i < 4; ++i) { S += red[2 * i]; Q += red[2 * i + 1]; }
    float mean = S * (1.f / D_MODEL);
    float var = Q * (1.f / D_MODEL) - mean * mean;
    red[0] = mean;
    red[1] = rsqrtf(var + 1e-5f);
  }
  __syncthreads();
  float mean = red[0], inv = red[1];
  const float4* wr = reinterpret_cast<const float4*>(w);
  const float4* br = reinterpret_cast<const float4*>(b);
  float4 wv = wr[tid], bv = br[tid];
  float4 o;
  o.x = (xv.x - mean) * inv * wv.x + bv.x;
  o.y = (xv.y - mean) * inv * wv.y + bv.y;
  o.z = (xv.z - mean) * inv * wv.z + bv.z;
  o.w = (xv.w - mean) * inv * wv.w + bv.w;
  reinterpret_cast<float4*>(xn + (size_t)t * D_MODEL)[tid] = o;
}

// ---------------------------------------------------------------------------
// Generic fp32 NT GEMM: C[M,N] = A[M,K] * B[N,K]^T  (+ epilogue)
// EPI 0: none; 1: softplus(v + bias[col]); 2: v + resid[row*ldr+col]
// ---------------------------------------------------------------------------
template <int EPI>
__global__ __launch_bounds__(256) void gemm_nt_kernel(
    const float* __restrict__ A, int lda, const float* __restrict__ B, int ldb,
    float* __restrict__ C, int ldc, int M, int N, int K,
    const float* __restrict__ bias, const float* __restrict__ resid, int ldr) {
  constexpr int BM = 64, BN = 64, BK = 16, TM = 4, TN = 4;
  __shared__ float As[BK][BM + 1];
  __shared__ float Bs[BK][BN + 1];
  int tid = threadIdx.x;
  int tx = tid & 15;
  int ty = tid >> 4;
  int row0 = blockIdx.y * BM;
  int col0 = blockIdx.x * BN;
  int lk = tid & (BK - 1);
  int lr = tid / BK;
  float acc[TM][TN] = {};
  for (int k0 = 0; k0 < K; k0 += BK) {
#pragma unroll
    for (int i = 0; i < 4; ++i) {
      int r = lr + 16 * i;
      int gr = row0 + r;
      float v = 0.f;
      if (gr < M) v = A[(size_t)gr * lda + k0 + lk];
      As[lk][r] = v;
    }
#pragma unroll
    for (int i = 0; i < 4; ++i) {
      int r = lr + 16 * i;
      int gc = col0 + r;
      float v = 0.f;
      if (gc < N) v = B[(size_t)gc * ldb + k0 + lk];
      Bs[lk][r] = v;
    }
    __syncthreads();
#pragma unroll
    for (int k = 0; k < BK; ++k) {
      float a[TM], bv[TN];
#pragma unroll
      for (int i = 0; i < TM; ++i) a[i] = As[k][ty * TM + i];
#pragma unroll
      for (int j = 0; j < TN; ++j) bv[j] = Bs[k][tx * TN + j];
#pragma unroll
      for (int i = 0; i < TM; ++i)
#pragma unroll
        for (int j = 0; j < TN; ++j) acc[i][j] += a[i] * bv[j];
    }
    __syncthreads();
  }
#pragma unroll
  for (int i = 0; i < TM; ++i) {
    int gr = row0 + ty * TM + i;
    if (gr >= M) continue;
#pragma unroll
    for (int j = 0; j < TN; ++j) {
      int gc = col0 + tx * TN + j;
      if (gc >= N) continue;
      float v = acc[i][j];
      if (EPI == 1) {
        float xv = v + bias[gc];
        v = fmaxf(xv, 0.f) + log1pf(expf(-fabsf(xv)));
      }
      if (EPI == 2) v += resid[(size_t)gr * ldr + gc];
      C[(size_t)gr * ldc + gc] = v;
    }
  }
}

// ---------------------------------------------------------------------------
// Depthwise causal conv (width 4) + SiLU. One thread per (t,d) element.
// ---------------------------------------------------------------------------
__global__ __launch_bounds__(256) void conv_silu_kernel(
    const float* __restrict__ u, const float* __restrict__ cw,
    const float* __restrict__ cb, float* __restrict__ uc) {
  size_t idx = (size_t)blockIdx.x * 256 + threadIdx.x;
  if (idx >= (size_t)TT * D_INNER) return;
  int d = (int)(idx & (D_INNER - 1));
  int t = (int)(idx >> 11);
  int l = t & (LL - 1);
  float acc = cb[d];
#pragma unroll
  for (int k = 0; k < D_CONV; ++k) {
    int ll = l - (D_CONV - 1) + k;
    if (ll >= 0) acc += u[idx - (size_t)(D_CONV - 1 - k) * D_INNER] * cw[d * D_CONV + k];
  }
  uc[idx] = acc / (1.f + expf(-acc));  // SiLU
}

// ---------------------------------------------------------------------------
// Segmented selective scan.
// Pass A (scan_partial): per (chan=b*D+d, n, seg): local scan from h=0 over
//   SEGLEN steps -> store h_end and prod(a). Block = 256 thr = 16 chan x 16 n.
//   grid = (NCHAN/16, NSEG).
// Pass B (scan_combine): per (chan,n): serial combine over NSEG segments;
//   writes segment initial state h_start in-place into the aprod buffer.
// Pass C (scan_final): same shape as A, h initialized from h_start; computes
//   y_t = (sum_n h*C + u*D) * silu(z), written by lane n==0.
// ---------------------------------------------------------------------------
__global__ __launch_bounds__(256) void scan_partial_kernel(
    const float* __restrict__ delta, const float* __restrict__ uc,
    const float* __restrict__ xd, const float* __restrict__ A_log,
    float* __restrict__ aprod_buf, float* __restrict__ hend_buf) {
  int tid = threadIdx.x;
  int n = tid & 15;
  int g = tid >> 4;
  int chan = blockIdx.x * 16 + g;
  int s = blockIdx.y;
  int b = chan >> 11;
  int d = chan & (D_INNER - 1);
  float Acoef = -expf(A_log[d * D_STATE + n]);
  float h = 0.f, ap = 1.f;
  size_t tbase = (size_t)b * LL + (size_t)s * SEGLEN;
  for (int l = 0; l < SEGLEN; ++l) {
    size_t t = tbase + l;
    float dl = delta[t * D_INNER + d];
    float ul = uc[t * D_INNER + d];
    float bn = xd[t * 96 + 64 + n];
    float a = __expf(dl * Acoef);
    h = a * h + dl * bn * ul;
    ap *= a;
  }
  size_t si = ((size_t)s * NCHAN + chan) * D_STATE + n;
  aprod_buf[si] = ap;
  hend_buf[si] = h;
}

__global__ __launch_bounds__(256) void scan_combine_kernel(
    float* __restrict__ aprod_buf, const float* __restrict__ hend_buf) {
  int idx = blockIdx.x * 256 + threadIdx.x;  // chan*16 + n, 65536 total
  float H = 0.f;
  for (int s = 0; s < NSEG; ++s) {
    size_t si = (size_t)s * (NCHAN * D_STATE) + idx;
    float a = aprod_buf[si];
    float he = hend_buf[si];
    aprod_buf[si] = H;          // h_start for segment s
    H = he + a * H;
  }
}

__global__ __launch_bounds__(256) void scan_final_kernel(
    const float* __restrict__ delta, const float* __restrict__ uc,
    const float* __restrict__ xd, const float* __restrict__ z,
    const float* __restrict__ A_log, const float* __restrict__ Dv,
    const float* __restrict__ hstart_buf, float* __restrict__ y) {
  int tid = threadIdx.x;
  int n = tid & 15;
  int g = tid >> 4;
  int chan = blockIdx.x * 16 + g;
  int s = blockIdx.y;
  int b = chan >> 11;
  int d = chan & (D_INNER - 1);
  float Acoef = -expf(A_log[d * D_STATE + n]);
  float Dd = Dv[d];
  float h = hstart_buf[((size_t)s * NCHAN + chan) * D_STATE + n];
  size_t tbase = (size_t)b * LL + (size_t)s * SEGLEN;
  for (int l = 0; l < SEGLEN; ++l) {
    size_t t = tbase + l;
    float dl = delta[t * D_INNER + d];
    float ul = uc[t * D_INNER + d];
    float bn = xd[t * 96 + 64 + n];
    float cn = xd[t * 96 + 80 + n];
    float a = __expf(dl * Acoef);
    h = a * h + dl * bn * ul;
    float p = h * cn;
    p += __shfl_xor(p, 1);
    p += __shfl_xor(p, 2);
    p += __shfl_xor(p, 4);
    p += __shfl_xor(p, 8);
    if (n == 0) {
      float zv = z[t * D_INNER + d];
      float sz = zv / (1.f + expf(-zv));
      y[t * D_INNER + d] = (p + ul * Dd) * sz;
    }
  }
}

// ---------------------------------------------------------------------------
extern "C" void kernel_launch(void* const* d_in, const int* in_sizes, int n_in,
                              void* d_out, int out_size, void* d_ws, size_t ws_size,
                              hipStream_t stream) {
  const float* x         = (const float*)d_in[0];
  const float* ln_w      = (const float*)d_in[1];
  const float* ln_b      = (const float*)d_in[2];
  const float* in_proj_w = (const float*)d_in[3];
  const float* conv_w    = (const float*)d_in[4];
  const float* conv_b    = (const float*)d_in[5];
  const float* x_proj_w  = (const float*)d_in[6];
  const float* dt_proj_w = (const float*)d_in[7];
  const float* dt_proj_b = (const float*)d_in[8];
  const float* A_log     = (const float*)d_in[9];
  const float* Dvec      = (const float*)d_in[10];
  const float* out_proj_w= (const float*)d_in[11];
  float* out = (float*)d_out;

  float* ws = (float*)d_ws;
  float* xn    = ws;                              // T*1024 (dead after in_proj; reused as aprod)
  float* u     = xn + (size_t)TT * D_MODEL;       // T*2048 (later reused as y)
  float* z     = u + (size_t)TT * D_INNER;        // T*2048
  float* uc    = z + (size_t)TT * D_INNER;        // T*2048
  float* xd    = uc + (size_t)TT * D_INNER;       // T*96
  float* delta = xd + (size_t)TT * 96;            // T*2048
  float* hend  = delta + (size_t)TT * D_INNER;    // NSEG*NCHAN*16 = T*1024
  float* aprod = xn;                              // NSEG*NCHAN*16 = T*1024 (aliases xn)

  // 1. LayerNorm
  layernorm_kernel<<<TT, 256, 0, stream>>>(x, ln_w, ln_b, xn);

  // 2. in_proj -> u, z
  gemm_nt_kernel<0><<<dim3(D_INNER / 64, TT / 64), 256, 0, stream>>>(
      xn, D_MODEL, in_proj_w, D_MODEL, u, D_INNER, TT, D_INNER, D_MODEL,
      nullptr, nullptr, 0);
  gemm_nt_kernel<0><<<dim3(D_INNER / 64, TT / 64), 256, 0, stream>>>(
      xn, D_MODEL, in_proj_w + (size_t)D_INNER * D_MODEL, D_MODEL, z, D_INNER,
      TT, D_INNER, D_MODEL, nullptr, nullptr, 0);

  // 3. causal depthwise conv + SiLU
  conv_silu_kernel<<<(TT * D_INNER) / 256, 256, 0, stream>>>(u, conv_w, conv_b, uc);

  // 4. x_proj -> x_dbl (N=96)
  gemm_nt_kernel<0><<<dim3(2, TT / 64), 256, 0, stream>>>(
      uc, D_INNER, x_proj_w, D_INNER, xd, 96, TT, 96, D_INNER,
      nullptr, nullptr, 0);

  // 5. dt_proj + softplus -> delta
  gemm_nt_kernel<1><<<dim3(D_INNER / 64, TT / 64), 256, 0, stream>>>(
      xd, 96, dt_proj_w, DT_RANK, delta, D_INNER, TT, D_INNER, DT_RANK,
      dt_proj_b, nullptr, 0);

  // 6. segmented selective scan + gate (writes y into the u buffer)
  scan_partial_kernel<<<dim3(NCHAN / 16, NSEG), 256, 0, stream>>>(
      delta, uc, xd, A_log, aprod, hend);
  scan_combine_kernel<<<(NCHAN * D_STATE) / 256, 256, 0, stream>>>(aprod, hend);
  scan_final_kernel<<<dim3(NCHAN / 16, NSEG), 256, 0, stream>>>(
      delta, uc, xd, z, A_log, Dvec, aprod, u);

  // 7. out_proj + residual
  gemm_nt_kernel<2><<<dim3(D_MODEL / 64, TT / 64), 256, 0, stream>>>(
      u, D_INNER, out_proj_w, D_INNER, out, D_MODEL, TT, D_MODEL, D_INNER,
      nullptr, x, D_MODEL);
}

// Round 3
// 617.948 us; speedup vs baseline: 5.4005x; 3.3081x over previous
//
#include <hip/hip_runtime.h>
#include <hip/hip_bf16.h>
#include <cstddef>

#define D_MODEL 1024
#define D_STATE 16
#define D_CONV 4
#define DT_RANK 64
#define D_INNER 2048
#define BB 2
#define LL 2048
#define TT (BB * LL)          // 4096 tokens
#define NSEG 64
#define SEGLEN (LL / NSEG)    // 32
#define NCHAN (BB * D_INNER)  // 4096

typedef __bf16 bf16x8 __attribute__((ext_vector_type(8)));
typedef float floatx4 __attribute__((ext_vector_type(4)));

__device__ __forceinline__ unsigned short f2bf(float f) {
  unsigned u = __float_as_uint(f);
  unsigned r = u + 0x7FFF + ((u >> 16) & 1);  // round-to-nearest-even
  return (unsigned short)(r >> 16);
}
__device__ __forceinline__ float b2f(unsigned short v) {
  return __uint_as_float((unsigned)v << 16);
}

// ---------------------------------------------------------------------------
// fp32 -> bf16 cast (n must be multiple of 4; one float4 per thread)
// ---------------------------------------------------------------------------
__global__ __launch_bounds__(256) void cast_bf16_kernel(
    const float* __restrict__ src, unsigned short* __restrict__ dst, int n4) {
  int i = blockIdx.x * 256 + threadIdx.x;
  if (i >= n4) return;
  float4 v = reinterpret_cast<const float4*>(src)[i];
  ushort4 o;
  o.x = f2bf(v.x); o.y = f2bf(v.y); o.z = f2bf(v.z); o.w = f2bf(v.w);
  reinterpret_cast<ushort4*>(dst)[i] = o;
}

// Repack dt columns (0..63) of xd (row stride 96, fp32) into bf16 (stride 64)
__global__ __launch_bounds__(256) void cast_dt_kernel(
    const float* __restrict__ xd, unsigned short* __restrict__ dtA) {
  int i = blockIdx.x * 256 + threadIdx.x;  // 65536 total
  int row = i >> 4, c = (i & 15) * 4;
  float4 v = *reinterpret_cast<const float4*>(xd + (size_t)row * 96 + c);
  ushort4 o;
  o.x = f2bf(v.x); o.y = f2bf(v.y); o.z = f2bf(v.z); o.w = f2bf(v.w);
  *reinterpret_cast<ushort4*>(dtA + (size_t)row * 64 + c) = o;
}

// ---------------------------------------------------------------------------
// LayerNorm: one block per token, 256 threads; bf16 output.
// ---------------------------------------------------------------------------
__global__ __launch_bounds__(256) void layernorm_kernel(
    const float* __restrict__ x, const float* __restrict__ w,
    const float* __restrict__ b, unsigned short* __restrict__ xn) {
  int t = blockIdx.x;
  int tid = threadIdx.x;
  const float4* xr = reinterpret_cast<const float4*>(x + (size_t)t * D_MODEL);
  float4 xv = xr[tid];
  float s = xv.x + xv.y + xv.z + xv.w;
  float sq = xv.x * xv.x + xv.y * xv.y + xv.z * xv.z + xv.w * xv.w;
  for (int off = 32; off >= 1; off >>= 1) {
    s += __shfl_down(s, off);
    sq += __shfl_down(sq, off);
  }
  __shared__ float red[8];
  int wave = tid >> 6;
  if ((tid & 63) == 0) { red[wave * 2] = s; red[wave * 2 + 1] = sq; }
  __syncthreads();
  if (tid == 0) {
    float S = 0.f, Q = 0.f;
    for (int i = 0; i < 4; ++i) { S += red[2 * i]; Q += red[2 * i + 1]; }
    float mean = S * (1.f / D_MODEL);
    float var = Q * (1.f / D_MODEL) - mean * mean;
    red[0] = mean;
    red[1] = rsqrtf(var + 1e-5f);
  }
  __syncthreads();
  float mean = red[0], inv = red[1];
  const float4* wr = reinterpret_cast<const float4*>(w);
  const float4* br = reinterpret_cast<const float4*>(b);
  float4 wv = wr[tid], bv = br[tid];
  ushort4 o;
  o.x = f2bf((xv.x - mean) * inv * wv.x + bv.x);
  o.y = f2bf((xv.y - mean) * inv * wv.y + bv.y);
  o.z = f2bf((xv.z - mean) * inv * wv.z + bv.z);
  o.w = f2bf((xv.w - mean) * inv * wv.w + bv.w);
  reinterpret_cast<ushort4*>(xn + (size_t)t * D_MODEL)[tid] = o;
}

// ---------------------------------------------------------------------------
// bf16 MFMA NT GEMM: C[M,N] (fp32) = A[M,K] * B[N,K]^T, A/B bf16 row-major.
// 128x128 tile, BK=32, 4 waves each computing 64x64 via 4x4 16x16x32 MFMA.
// global_load_lds (16B/lane) with XOR-swizzled LDS slots (2-way = free).
// M, K must be multiples of 128/32; N arbitrary (clamped loads, masked store).
// EPI 0: none; 1: softplus(v + bias[col]); 2: v + resid[row*ldr+col]
// ---------------------------------------------------------------------------
template <int EPI>
__global__ __launch_bounds__(256) void gemm_bf16_kernel(
    const unsigned short* __restrict__ A, int lda,
    const unsigned short* __restrict__ B, int ldb,
    float* __restrict__ C, int ldc, int M, int N, int K,
    const float* __restrict__ bias, const float* __restrict__ resid, int ldr) {
  __shared__ unsigned short Atile[128 * 32];
  __shared__ unsigned short Btile[128 * 32];
  const int tid = threadIdx.x;
  const int lane = tid & 63;
  const int wv = tid >> 6;          // wave 0..3
  const int wrow = (wv >> 1) * 64;  // wave row offset in tile
  const int wcol = (wv & 1) * 64;   // wave col offset in tile
  const int row0 = blockIdx.y * 128;
  const int col0 = blockIdx.x * 128;
  const int m = lane & 15;
  const int q = lane >> 4;

  floatx4 acc[4][4] = {};

  // precompute staging slots (2 per wave per tile)
  int slot0 = wv * 128 + lane;
  int slot1 = slot0 + 64;  // wv*128 + 64 + lane

  for (int k0 = 0; k0 < K; k0 += 32) {
#pragma unroll
    for (int t = 0; t < 2; ++t) {
      int slot = t == 0 ? slot0 : slot1;
      int row = slot >> 2;
      int kg = (slot & 3) ^ ((row >> 1) & 3);
      const unsigned short* ga = A + (size_t)(row0 + row) * lda + k0 + kg * 8;
      __builtin_amdgcn_global_load_lds(
          (const __attribute__((address_space(1))) void*)ga,
          (__attribute__((address_space(3))) void*)(Atile + slot * 8), 16, 0, 0);
      int rowB = col0 + row;
      if (rowB >= N) rowB = N - 1;  // clamp (x_proj N=96)
      const unsigned short* gb = B + (size_t)rowB * ldb + k0 + kg * 8;
      __builtin_amdgcn_global_load_lds(
          (const __attribute__((address_space(1))) void*)gb,
          (__attribute__((address_space(3))) void*)(Btile + slot * 8), 16, 0, 0);
    }
    __syncthreads();
    bf16x8 af[4], bfr[4];
#pragma unroll
    for (int i = 0; i < 4; ++i) {
      int ra = wrow + i * 16 + m;
      int sa = ra * 4 + (q ^ ((ra >> 1) & 3));
      af[i] = *reinterpret_cast<const bf16x8*>(Atile + sa * 8);
      int rb = wcol + i * 16 + m;
      int sb = rb * 4 + (q ^ ((rb >> 1) & 3));
      bfr[i] = *reinterpret_cast<const bf16x8*>(Btile + sb * 8);
    }
#pragma unroll
    for (int i = 0; i < 4; ++i)
#pragma unroll
      for (int j = 0; j < 4; ++j)
        acc[i][j] = __builtin_amdgcn_mfma_f32_16x16x32_bf16(
            af[i], bfr[j], acc[i][j], 0, 0, 0);
    __syncthreads();
  }

  // epilogue: C/D layout col = lane&15, row = q*4 + reg
#pragma unroll
  for (int j = 0; j < 4; ++j) {
    int gc = col0 + wcol + j * 16 + m;
    if (gc >= N) continue;
#pragma unroll
    for (int i = 0; i < 4; ++i) {
#pragma unroll
      for (int r = 0; r < 4; ++r) {
        int gr = row0 + wrow + i * 16 + q * 4 + r;
        float v = acc[i][j][r];
        if (EPI == 1) {
          float xv = v + bias[gc];
          v = fmaxf(xv, 0.f) + log1pf(expf(-fabsf(xv)));
        }
        if (EPI == 2) v += resid[(size_t)gr * ldr + gc];
        C[(size_t)gr * ldc + gc] = v;
      }
    }
  }
}

// ---------------------------------------------------------------------------
// Depthwise causal conv (width 4) + SiLU; fp32 in, bf16 out.
// ---------------------------------------------------------------------------
__global__ __launch_bounds__(256) void conv_silu_kernel(
    const float* __restrict__ u, const float* __restrict__ cw,
    const float* __restrict__ cb, unsigned short* __restrict__ ucb) {
  size_t idx = (size_t)blockIdx.x * 256 + threadIdx.x;
  if (idx >= (size_t)TT * D_INNER) return;
  int d = (int)(idx & (D_INNER - 1));
  int t = (int)(idx >> 11);
  int l = t & (LL - 1);
  float acc = cb[d];
#pragma unroll
  for (int k = 0; k < D_CONV; ++k) {
    int ll = l - (D_CONV - 1) + k;
    if (ll >= 0) acc += u[idx - (size_t)(D_CONV - 1 - k) * D_INNER] * cw[d * D_CONV + k];
  }
  ucb[idx] = f2bf(acc / (1.f + expf(-acc)));  // SiLU
}

// ---------------------------------------------------------------------------
// Segmented selective scan (3 passes). u in bf16, delta/xd/z fp32.
// ---------------------------------------------------------------------------
__global__ __launch_bounds__(256) void scan_partial_kernel(
    const float* __restrict__ delta, const unsigned short* __restrict__ ucb,
    const float* __restrict__ xd, const float* __restrict__ A_log,
    float* __restrict__ aprod_buf, float* __restrict__ hend_buf) {
  int tid = threadIdx.x;
  int n = tid & 15;
  int g = tid >> 4;
  int chan = blockIdx.x * 16 + g;
  int s = blockIdx.y;
  int b = chan >> 11;
  int d = chan & (D_INNER - 1);
  float Acoef = -expf(A_log[d * D_STATE + n]);
  float h = 0.f, ap = 1.f;
  size_t tbase = (size_t)b * LL + (size_t)s * SEGLEN;
  for (int l = 0; l < SEGLEN; ++l) {
    size_t t = tbase + l;
    float dl = delta[t * D_INNER + d];
    float ul = b2f(ucb[t * D_INNER + d]);
    float bn = xd[t * 96 + 64 + n];
    float a = __expf(dl * Acoef);
    h = a * h + dl * bn * ul;
    ap *= a;
  }
  size_t si = ((size_t)s * NCHAN + chan) * D_STATE + n;
  aprod_buf[si] = ap;
  hend_buf[si] = h;
}

__global__ __launch_bounds__(256) void scan_combine_kernel(
    float* __restrict__ aprod_buf, const float* __restrict__ hend_buf) {
  int idx = blockIdx.x * 256 + threadIdx.x;  // chan*16 + n, 65536 total
  float H = 0.f;
  for (int s = 0; s < NSEG; ++s) {
    size_t si = (size_t)s * (NCHAN * D_STATE) + idx;
    float a = aprod_buf[si];
    float he = hend_buf[si];
    aprod_buf[si] = H;  // h_start for segment s
    H = he + a * H;
  }
}

__global__ __launch_bounds__(256) void scan_final_kernel(
    const float* __restrict__ delta, const unsigned short* ucb,
    const float* __restrict__ xd, const float* __restrict__ z,
    const float* __restrict__ A_log, const float* __restrict__ Dv,
    const float* __restrict__ hstart_buf, unsigned short* yb) {
  int tid = threadIdx.x;
  int n = tid & 15;
  int g = tid >> 4;
  int chan = blockIdx.x * 16 + g;
  int s = blockIdx.y;
  int b = chan >> 11;
  int d = chan & (D_INNER - 1);
  float Acoef = -expf(A_log[d * D_STATE + n]);
  float Dd = Dv[d];
  float h = hstart_buf[((size_t)s * NCHAN + chan) * D_STATE + n];
  size_t tbase = (size_t)b * LL + (size_t)s * SEGLEN;
  for (int l = 0; l < SEGLEN; ++l) {
    size_t t = tbase + l;
    float dl = delta[t * D_INNER + d];
    float ul = b2f(ucb[t * D_INNER + d]);
    float bn = xd[t * 96 + 64 + n];
    float cn = xd[t * 96 + 80 + n];
    float a = __expf(dl * Acoef);
    h = a * h + dl * bn * ul;
    float p = h * cn;
    p += __shfl_xor(p, 1);
    p += __shfl_xor(p, 2);
    p += __shfl_xor(p, 4);
    p += __shfl_xor(p, 8);
    if (n == 0) {
      float zv = z[t * D_INNER + d];
      float sz = zv / (1.f + expf(-zv));
      yb[t * D_INNER + d] = f2bf((p + ul * Dd) * sz);  // in-place over ucb: safe
    }
  }
}

// ---------------------------------------------------------------------------
extern "C" void kernel_launch(void* const* d_in, const int* in_sizes, int n_in,
                              void* d_out, int out_size, void* d_ws, size_t ws_size,
                              hipStream_t stream) {
  const float* x         = (const float*)d_in[0];
  const float* ln_w      = (const float*)d_in[1];
  const float* ln_b      = (const float*)d_in[2];
  const float* in_proj_w = (const float*)d_in[3];
  const float* conv_w    = (const float*)d_in[4];
  const float* conv_b    = (const float*)d_in[5];
  const float* x_proj_w  = (const float*)d_in[6];
  const float* dt_proj_w = (const float*)d_in[7];
  const float* dt_proj_b = (const float*)d_in[8];
  const float* A_log     = (const float*)d_in[9];
  const float* Dvec      = (const float*)d_in[10];
  const float* out_proj_w= (const float*)d_in[11];
  float* out = (float*)d_out;

  // workspace layout (all counts multiples of 8 -> 16B alignment everywhere)
  unsigned short* wip = (unsigned short*)d_ws;          // 4194304 (in_proj_w bf16)
  unsigned short* wop = wip + 4194304;                  // 2097152 (out_proj_w)
  unsigned short* wxp = wop + 2097152;                  // 196608  (x_proj_w)
  unsigned short* wdt = wxp + 196608;                   // 131072  (dt_proj_w)
  unsigned short* xnb = wdt + 131072;                   // T*1024 bf16
  unsigned short* ucb = xnb + (size_t)TT * D_MODEL;     // T*2048 bf16 (conv out; scan rewrites as y)
  unsigned short* dtA = ucb + (size_t)TT * D_INNER;     // T*64 bf16
  float* u     = (float*)(dtA + (size_t)TT * DT_RANK);  // T*2048 f32 (reused as delta)
  float* z     = u + (size_t)TT * D_INNER;              // T*2048 f32
  float* xd    = z + (size_t)TT * D_INNER;              // T*96 f32
  float* hend  = xd + (size_t)TT * 96;                  // NSEG*NCHAN*16
  float* aprod = hend + (size_t)NSEG * NCHAN * D_STATE; // NSEG*NCHAN*16
  float* delta = u;

  // 0. weight casts
  cast_bf16_kernel<<<4194304 / 1024, 256, 0, stream>>>(in_proj_w, wip, 4194304 / 4);
  cast_bf16_kernel<<<2097152 / 1024, 256, 0, stream>>>(out_proj_w, wop, 2097152 / 4);
  cast_bf16_kernel<<<196608 / 1024, 256, 0, stream>>>(x_proj_w, wxp, 196608 / 4);
  cast_bf16_kernel<<<131072 / 1024, 256, 0, stream>>>(dt_proj_w, wdt, 131072 / 4);

  // 1. LayerNorm -> bf16
  layernorm_kernel<<<TT, 256, 0, stream>>>(x, ln_w, ln_b, xnb);

  // 2. in_proj -> u, z (fp32)
  gemm_bf16_kernel<0><<<dim3(D_INNER / 128, TT / 128), 256, 0, stream>>>(
      xnb, D_MODEL, wip, D_MODEL, u, D_INNER, TT, D_INNER, D_MODEL,
      nullptr, nullptr, 0);
  gemm_bf16_kernel<0><<<dim3(D_INNER / 128, TT / 128), 256, 0, stream>>>(
      xnb, D_MODEL, wip + (size_t)D_INNER * D_MODEL, D_MODEL, z, D_INNER,
      TT, D_INNER, D_MODEL, nullptr, nullptr, 0);

  // 3. causal depthwise conv + SiLU -> bf16
  conv_silu_kernel<<<(TT * D_INNER) / 256, 256, 0, stream>>>(u, conv_w, conv_b, ucb);

  // 4. x_proj -> xd fp32 (N=96)
  gemm_bf16_kernel<0><<<dim3(1, TT / 128), 256, 0, stream>>>(
      ucb, D_INNER, wxp, D_INNER, xd, 96, TT, 96, D_INNER,
      nullptr, nullptr, 0);

  // 5. dt repack + dt_proj + softplus -> delta (overwrites u)
  cast_dt_kernel<<<(TT * DT_RANK / 4) / 256, 256, 0, stream>>>(xd, dtA);
  gemm_bf16_kernel<1><<<dim3(D_INNER / 128, TT / 128), 256, 0, stream>>>(
      dtA, DT_RANK, wdt, DT_RANK, delta, D_INNER, TT, D_INNER, DT_RANK,
      dt_proj_b, nullptr, 0);

  // 6. segmented selective scan + gate -> y bf16 (in ucb)
  scan_partial_kernel<<<dim3(NCHAN / 16, NSEG), 256, 0, stream>>>(
      delta, ucb, xd, A_log, aprod, hend);
  scan_combine_kernel<<<(NCHAN * D_STATE) / 256, 256, 0, stream>>>(aprod, hend);
  scan_final_kernel<<<dim3(NCHAN / 16, NSEG), 256, 0, stream>>>(
      delta, ucb, xd, z, A_log, Dvec, aprod, ucb);

  // 7. out_proj + residual
  gemm_bf16_kernel<2><<<dim3(D_MODEL / 128, TT / 128), 256, 0, stream>>>(
      ucb, D_INNER, wop, D_INNER, out, D_MODEL, TT, D_MODEL, D_INNER,
      nullptr, x, D_MODEL);
}

// Round 4
// 408.172 us; speedup vs baseline: 8.1760x; 1.5139x over previous
//
#include <hip/hip_runtime.h>
#include <hip/hip_bf16.h>
#include <cstddef>

#define D_MODEL 1024
#define D_STATE 16
#define D_CONV 4
#define DT_RANK 64
#define D_INNER 2048
#define BB 2
#define LL 2048
#define TT (BB * LL)          // 4096 tokens
#define NSEG 64
#define SEGLEN (LL / NSEG)    // 32
#define NCHAN (BB * D_INNER)  // 4096

typedef __bf16 bf16x8 __attribute__((ext_vector_type(8)));
typedef float floatx4 __attribute__((ext_vector_type(4)));

__device__ __forceinline__ unsigned short f2bf(float f) {
  unsigned u = __float_as_uint(f);
  unsigned r = u + 0x7FFF + ((u >> 16) & 1);  // round-to-nearest-even
  return (unsigned short)(r >> 16);
}
__device__ __forceinline__ float b2f(unsigned short v) {
  return __uint_as_float((unsigned)v << 16);
}

// ---------------------------------------------------------------------------
// fp32 -> bf16 cast (n must be multiple of 4; one float4 per thread)
// ---------------------------------------------------------------------------
__global__ __launch_bounds__(256) void cast_bf16_kernel(
    const float* __restrict__ src, unsigned short* __restrict__ dst, int n4) {
  int i = blockIdx.x * 256 + threadIdx.x;
  if (i >= n4) return;
  float4 v = reinterpret_cast<const float4*>(src)[i];
  ushort4 o;
  o.x = f2bf(v.x); o.y = f2bf(v.y); o.z = f2bf(v.z); o.w = f2bf(v.w);
  reinterpret_cast<ushort4*>(dst)[i] = o;
}

// Repack dt columns (0..63) of xd (row stride 96, fp32) into bf16 (stride 64)
__global__ __launch_bounds__(256) void cast_dt_kernel(
    const float* __restrict__ xd, unsigned short* __restrict__ dtA) {
  int i = blockIdx.x * 256 + threadIdx.x;  // 65536 total
  int row = i >> 4, c = (i & 15) * 4;
  float4 v = *reinterpret_cast<const float4*>(xd + (size_t)row * 96 + c);
  ushort4 o;
  o.x = f2bf(v.x); o.y = f2bf(v.y); o.z = f2bf(v.z); o.w = f2bf(v.w);
  *reinterpret_cast<ushort4*>(dtA + (size_t)row * 64 + c) = o;
}

// ---------------------------------------------------------------------------
// LayerNorm: one block per token, 256 threads; bf16 output.
// ---------------------------------------------------------------------------
__global__ __launch_bounds__(256) void layernorm_kernel(
    const float* __restrict__ x, const float* __restrict__ w,
    const float* __restrict__ b, unsigned short* __restrict__ xn) {
  int t = blockIdx.x;
  int tid = threadIdx.x;
  const float4* xr = reinterpret_cast<const float4*>(x + (size_t)t * D_MODEL);
  float4 xv = xr[tid];
  float s = xv.x + xv.y + xv.z + xv.w;
  float sq = xv.x * xv.x + xv.y * xv.y + xv.z * xv.z + xv.w * xv.w;
  for (int off = 32; off >= 1; off >>= 1) {
    s += __shfl_down(s, off);
    sq += __shfl_down(sq, off);
  }
  __shared__ float red[8];
  int wave = tid >> 6;
  if ((tid & 63) == 0) { red[wave * 2] = s; red[wave * 2 + 1] = sq; }
  __syncthreads();
  if (tid == 0) {
    float S = 0.f, Q = 0.f;
    for (int i = 0; i < 4; ++i) { S += red[2 * i]; Q += red[2 * i + 1]; }
    float mean = S * (1.f / D_MODEL);
    float var = Q * (1.f / D_MODEL) - mean * mean;
    red[0] = mean;
    red[1] = rsqrtf(var + 1e-5f);
  }
  __syncthreads();
  float mean = red[0], inv = red[1];
  const float4* wr = reinterpret_cast<const float4*>(w);
  const float4* br = reinterpret_cast<const float4*>(b);
  float4 wv = wr[tid], bv = br[tid];
  ushort4 o;
  o.x = f2bf((xv.x - mean) * inv * wv.x + bv.x);
  o.y = f2bf((xv.y - mean) * inv * wv.y + bv.y);
  o.z = f2bf((xv.z - mean) * inv * wv.z + bv.z);
  o.w = f2bf((xv.w - mean) * inv * wv.w + bv.w);
  reinterpret_cast<ushort4*>(xn + (size_t)t * D_MODEL)[tid] = o;
}

// ---------------------------------------------------------------------------
// bf16 MFMA NT GEMM: C[M,N] = A[M,K] * B[N,K]^T, A/B bf16 row-major.
// 128x128 tile, BK=32, 4 waves each computing 64x64 via 4x4 16x16x32 MFMA.
// EPI 0: none (f32 out); 1: softplus(v+bias[col]) (f32); 2: v+resid (f32);
// EPI 3: silu(v) -> bf16 out.
// ---------------------------------------------------------------------------
template <int EPI, typename OT>
__global__ __launch_bounds__(256) void gemm_bf16_kernel(
    const unsigned short* __restrict__ A, int lda,
    const unsigned short* __restrict__ B, int ldb,
    OT* __restrict__ C, int ldc, int M, int N, int K,
    const float* __restrict__ bias, const float* __restrict__ resid, int ldr) {
  __shared__ unsigned short Atile[128 * 32];
  __shared__ unsigned short Btile[128 * 32];
  const int tid = threadIdx.x;
  const int lane = tid & 63;
  const int wv = tid >> 6;
  const int wrow = (wv >> 1) * 64;
  const int wcol = (wv & 1) * 64;
  const int row0 = blockIdx.y * 128;
  const int col0 = blockIdx.x * 128;
  const int m = lane & 15;
  const int q = lane >> 4;

  floatx4 acc[4][4] = {};
  int slot0 = wv * 128 + lane;
  int slot1 = slot0 + 64;

  for (int k0 = 0; k0 < K; k0 += 32) {
#pragma unroll
    for (int t = 0; t < 2; ++t) {
      int slot = t == 0 ? slot0 : slot1;
      int row = slot >> 2;
      int kg = (slot & 3) ^ ((row >> 1) & 3);
      const unsigned short* ga = A + (size_t)(row0 + row) * lda + k0 + kg * 8;
      __builtin_amdgcn_global_load_lds(
          (const __attribute__((address_space(1))) void*)ga,
          (__attribute__((address_space(3))) void*)(Atile + slot * 8), 16, 0, 0);
      int rowB = col0 + row;
      if (rowB >= N) rowB = N - 1;  // clamp (x_proj N=96)
      const unsigned short* gb = B + (size_t)rowB * ldb + k0 + kg * 8;
      __builtin_amdgcn_global_load_lds(
          (const __attribute__((address_space(1))) void*)gb,
          (__attribute__((address_space(3))) void*)(Btile + slot * 8), 16, 0, 0);
    }
    __syncthreads();
    bf16x8 af[4], bfr[4];
#pragma unroll
    for (int i = 0; i < 4; ++i) {
      int ra = wrow + i * 16 + m;
      int sa = ra * 4 + (q ^ ((ra >> 1) & 3));
      af[i] = *reinterpret_cast<const bf16x8*>(Atile + sa * 8);
      int rb = wcol + i * 16 + m;
      int sb = rb * 4 + (q ^ ((rb >> 1) & 3));
      bfr[i] = *reinterpret_cast<const bf16x8*>(Btile + sb * 8);
    }
#pragma unroll
    for (int i = 0; i < 4; ++i)
#pragma unroll
      for (int j = 0; j < 4; ++j)
        acc[i][j] = __builtin_amdgcn_mfma_f32_16x16x32_bf16(
            af[i], bfr[j], acc[i][j], 0, 0, 0);
    __syncthreads();
  }

#pragma unroll
  for (int j = 0; j < 4; ++j) {
    int gc = col0 + wcol + j * 16 + m;
    if (gc >= N) continue;
#pragma unroll
    for (int i = 0; i < 4; ++i) {
#pragma unroll
      for (int r = 0; r < 4; ++r) {
        int gr = row0 + wrow + i * 16 + q * 4 + r;
        float v = acc[i][j][r];
        if (EPI == 1) {
          float xv = v + bias[gc];
          v = fmaxf(xv, 0.f) + log1pf(expf(-fabsf(xv)));
        }
        if (EPI == 2) v += resid[(size_t)gr * ldr + gc];
        if (EPI == 3) {
          float sv = v / (1.f + expf(-v));
          ((unsigned short*)C)[(size_t)gr * ldc + gc] = f2bf(sv);
        } else {
          ((float*)C)[(size_t)gr * ldc + gc] = v;
        }
      }
    }
  }
}

// ---------------------------------------------------------------------------
// Depthwise causal conv (width 4) + SiLU; fp32 in, bf16 out.
// ---------------------------------------------------------------------------
__global__ __launch_bounds__(256) void conv_silu_kernel(
    const float* __restrict__ u, const float* __restrict__ cw,
    const float* __restrict__ cb, unsigned short* __restrict__ ucb) {
  size_t idx = (size_t)blockIdx.x * 256 + threadIdx.x;
  if (idx >= (size_t)TT * D_INNER) return;
  int d = (int)(idx & (D_INNER - 1));
  int t = (int)(idx >> 11);
  int l = t & (LL - 1);
  float acc = cb[d];
#pragma unroll
  for (int k = 0; k < D_CONV; ++k) {
    int ll = l - (D_CONV - 1) + k;
    if (ll >= 0) acc += u[idx - (size_t)(D_CONV - 1 - k) * D_INNER] * cw[d * D_CONV + k];
  }
  ucb[idx] = f2bf(acc / (1.f + expf(-acc)));  // SiLU
}

// ---------------------------------------------------------------------------
// Segmented selective scan, channel-per-thread: each thread owns channel d
// with h[16] in registers (float4 x 4 -> v_pk_fma_f32). Block = 256 channels
// of one (batch, segment); B (and C) staged in LDS, read as broadcast b128.
// exp via exp2 with log2(e) folded into Acoef. prod(a) telescopes to
// exp2(Acoef * sum(dl)).
// ---------------------------------------------------------------------------
__global__ __launch_bounds__(256) void scan_partial_kernel(
    const float* __restrict__ delta, const unsigned short* __restrict__ ucb,
    const float* __restrict__ xd, const float* __restrict__ A_log,
    float* __restrict__ aprod_buf, float* __restrict__ hend_buf) {
  __shared__ float Bs[SEGLEN][16];
  const int tid = threadIdx.x;
  const int d = blockIdx.x * 256 + tid;
  const int s = blockIdx.y;
  const int b = blockIdx.z;
  const int chan = b * D_INNER + d;
  const size_t tbase = (size_t)b * LL + (size_t)s * SEGLEN;

  // stage B: 32 rows x 16 floats; thread i -> row i>>3, float2 (i&7)*2
  {
    int row = tid >> 3, pair = tid & 7;
    *reinterpret_cast<float2*>(&Bs[row][pair * 2]) =
        *reinterpret_cast<const float2*>(xd + (tbase + row) * 96 + 64 + pair * 2);
  }
  // Acoef = -exp(A_log) * log2(e)
  floatx4 Ac[4];
  {
    const floatx4* ar = reinterpret_cast<const floatx4*>(A_log + (size_t)d * D_STATE);
#pragma unroll
    for (int k = 0; k < 4; ++k) {
      floatx4 v = ar[k];
      for (int j = 0; j < 4; ++j) Ac[k][j] = -__expf(v[j]) * 1.4426950408889634f;
    }
  }
  __syncthreads();

  floatx4 h[4] = {};
  float S = 0.f;
  for (int l = 0; l < SEGLEN; ++l) {
    size_t t = tbase + l;
    float dl = delta[t * D_INNER + d];
    float ul = b2f(ucb[t * D_INNER + d]);
    float dlul = dl * ul;
    S += dl;
#pragma unroll
    for (int k = 0; k < 4; ++k) {
      floatx4 bv = *reinterpret_cast<const floatx4*>(&Bs[l][k * 4]);
      floatx4 a;
      for (int j = 0; j < 4; ++j) a[j] = __builtin_amdgcn_exp2f(dl * Ac[k][j]);
      h[k] = a * h[k] + dlul * bv;
    }
  }
  size_t base = ((size_t)s * NCHAN + chan) * D_STATE;
#pragma unroll
  for (int k = 0; k < 4; ++k) {
    floatx4 ap;
    for (int j = 0; j < 4; ++j) ap[j] = __builtin_amdgcn_exp2f(S * Ac[k][j]);
    *reinterpret_cast<floatx4*>(hend_buf + base + k * 4) = h[k];
    *reinterpret_cast<floatx4*>(aprod_buf + base + k * 4) = ap;
  }
}

__global__ __launch_bounds__(256) void scan_combine_kernel(
    float* __restrict__ aprod_buf, const float* __restrict__ hend_buf) {
  int idx = blockIdx.x * 256 + threadIdx.x;  // chan*16 + n, 65536 total
  float H = 0.f;
  for (int s = 0; s < NSEG; ++s) {
    size_t si = (size_t)s * (NCHAN * D_STATE) + idx;
    float a = aprod_buf[si];
    float he = hend_buf[si];
    aprod_buf[si] = H;  // h_start for segment s
    H = he + a * H;
  }
}

__global__ __launch_bounds__(256) void scan_final_kernel(
    const float* __restrict__ delta, const unsigned short* __restrict__ ucb,
    const float* __restrict__ xd, const unsigned short* __restrict__ zsb,
    const float* __restrict__ A_log, const float* __restrict__ Dv,
    const float* __restrict__ hstart_buf, unsigned short* __restrict__ yb) {
  __shared__ float BCs[SEGLEN][32];
  const int tid = threadIdx.x;
  const int d = blockIdx.x * 256 + tid;
  const int s = blockIdx.y;
  const int b = blockIdx.z;
  const int chan = b * D_INNER + d;
  const size_t tbase = (size_t)b * LL + (size_t)s * SEGLEN;

  // stage B+C: 32 rows x 32 floats; thread i -> row i>>3, float4 (i&7)*4
  {
    int row = tid >> 3, quad = tid & 7;
    *reinterpret_cast<float4*>(&BCs[row][quad * 4]) =
        *reinterpret_cast<const float4*>(xd + (tbase + row) * 96 + 64 + quad * 4);
  }
  floatx4 Ac[4];
  {
    const floatx4* ar = reinterpret_cast<const floatx4*>(A_log + (size_t)d * D_STATE);
#pragma unroll
    for (int k = 0; k < 4; ++k) {
      floatx4 v = ar[k];
      for (int j = 0; j < 4; ++j) Ac[k][j] = -__expf(v[j]) * 1.4426950408889634f;
    }
  }
  float Dd = Dv[d];
  floatx4 h[4];
  {
    size_t base = ((size_t)s * NCHAN + chan) * D_STATE;
#pragma unroll
    for (int k = 0; k < 4; ++k)
      h[k] = *reinterpret_cast<const floatx4*>(hstart_buf + base + k * 4);
  }
  __syncthreads();

  for (int l = 0; l < SEGLEN; ++l) {
    size_t t = tbase + l;
    float dl = delta[t * D_INNER + d];
    float ul = b2f(ucb[t * D_INNER + d]);
    float dlul = dl * ul;
    floatx4 psum = {};
#pragma unroll
    for (int k = 0; k < 4; ++k) {
      floatx4 bv = *reinterpret_cast<const floatx4*>(&BCs[l][k * 4]);
      floatx4 cv = *reinterpret_cast<const floatx4*>(&BCs[l][16 + k * 4]);
      floatx4 a;
      for (int j = 0; j < 4; ++j) a[j] = __builtin_amdgcn_exp2f(dl * Ac[k][j]);
      h[k] = a * h[k] + dlul * bv;
      psum += h[k] * cv;
    }
    float p = psum[0] + psum[1] + psum[2] + psum[3];
    float zs = b2f(zsb[t * D_INNER + d]);
    yb[t * D_INNER + d] = f2bf((p + ul * Dd) * zs);  // in-place over ucb: safe
  }
}

// ---------------------------------------------------------------------------
extern "C" void kernel_launch(void* const* d_in, const int* in_sizes, int n_in,
                              void* d_out, int out_size, void* d_ws, size_t ws_size,
                              hipStream_t stream) {
  const float* x         = (const float*)d_in[0];
  const float* ln_w      = (const float*)d_in[1];
  const float* ln_b      = (const float*)d_in[2];
  const float* in_proj_w = (const float*)d_in[3];
  const float* conv_w    = (const float*)d_in[4];
  const float* conv_b    = (const float*)d_in[5];
  const float* x_proj_w  = (const float*)d_in[6];
  const float* dt_proj_w = (const float*)d_in[7];
  const float* dt_proj_b = (const float*)d_in[8];
  const float* A_log     = (const float*)d_in[9];
  const float* Dvec      = (const float*)d_in[10];
  const float* out_proj_w= (const float*)d_in[11];
  float* out = (float*)d_out;

  // workspace layout (16B-aligned segments)
  unsigned short* wip = (unsigned short*)d_ws;          // 4194304
  unsigned short* wop = wip + 4194304;                  // 2097152
  unsigned short* wxp = wop + 2097152;                  // 196608
  unsigned short* wdt = wxp + 196608;                   // 131072
  unsigned short* xnb = wdt + 131072;                   // T*1024
  unsigned short* ucb = xnb + (size_t)TT * D_MODEL;     // T*2048 (conv out -> y)
  unsigned short* zsb = ucb + (size_t)TT * D_INNER;     // T*2048 (silu(z) bf16)
  unsigned short* dtA = zsb + (size_t)TT * D_INNER;     // T*64
  float* u     = (float*)(dtA + (size_t)TT * DT_RANK);  // T*2048 f32 (reused as delta)
  float* xd    = u + (size_t)TT * D_INNER;              // T*96 f32
  float* hend  = xd + (size_t)TT * 96;                  // NSEG*NCHAN*16
  float* aprod = hend + (size_t)NSEG * NCHAN * D_STATE; // NSEG*NCHAN*16
  float* delta = u;

  // 0. weight casts
  cast_bf16_kernel<<<4194304 / 1024, 256, 0, stream>>>(in_proj_w, wip, 4194304 / 4);
  cast_bf16_kernel<<<2097152 / 1024, 256, 0, stream>>>(out_proj_w, wop, 2097152 / 4);
  cast_bf16_kernel<<<196608 / 1024, 256, 0, stream>>>(x_proj_w, wxp, 196608 / 4);
  cast_bf16_kernel<<<131072 / 1024, 256, 0, stream>>>(dt_proj_w, wdt, 131072 / 4);

  // 1. LayerNorm -> bf16
  layernorm_kernel<<<TT, 256, 0, stream>>>(x, ln_w, ln_b, xnb);

  // 2. in_proj -> u (f32), silu(z) (bf16)
  gemm_bf16_kernel<0, float><<<dim3(D_INNER / 128, TT / 128), 256, 0, stream>>>(
      xnb, D_MODEL, wip, D_MODEL, u, D_INNER, TT, D_INNER, D_MODEL,
      nullptr, nullptr, 0);
  gemm_bf16_kernel<3, unsigned short><<<dim3(D_INNER / 128, TT / 128), 256, 0, stream>>>(
      xnb, D_MODEL, wip + (size_t)D_INNER * D_MODEL, D_MODEL, zsb, D_INNER,
      TT, D_INNER, D_MODEL, nullptr, nullptr, 0);

  // 3. causal depthwise conv + SiLU -> bf16
  conv_silu_kernel<<<(TT * D_INNER) / 256, 256, 0, stream>>>(u, conv_w, conv_b, ucb);

  // 4. x_proj -> xd f32 (N=96)
  gemm_bf16_kernel<0, float><<<dim3(1, TT / 128), 256, 0, stream>>>(
      ucb, D_INNER, wxp, D_INNER, xd, 96, TT, 96, D_INNER,
      nullptr, nullptr, 0);

  // 5. dt repack + dt_proj + softplus -> delta (overwrites u)
  cast_dt_kernel<<<(TT * DT_RANK / 4) / 256, 256, 0, stream>>>(xd, dtA);
  gemm_bf16_kernel<1, float><<<dim3(D_INNER / 128, TT / 128), 256, 0, stream>>>(
      dtA, DT_RANK, wdt, DT_RANK, delta, D_INNER, TT, D_INNER, DT_RANK,
      dt_proj_b, nullptr, 0);

  // 6. segmented selective scan + gate -> y bf16 (in ucb)
  scan_partial_kernel<<<dim3(D_INNER / 256, NSEG, BB), 256, 0, stream>>>(
      delta, ucb, xd, A_log, aprod, hend);
  scan_combine_kernel<<<(NCHAN * D_STATE) / 256, 256, 0, stream>>>(aprod, hend);
  scan_final_kernel<<<dim3(D_INNER / 256, NSEG, BB), 256, 0, stream>>>(
      delta, ucb, xd, zsb, A_log, Dvec, aprod, ucb);

  // 7. out_proj + residual
  gemm_bf16_kernel<2, float><<<dim3(D_MODEL / 128, TT / 128), 256, 0, stream>>>(
      ucb, D_INNER, wop, D_INNER, out, D_MODEL, TT, D_MODEL, D_INNER,
      nullptr, x, D_MODEL);
}

// Round 5
// 381.826 us; speedup vs baseline: 8.7402x; 1.0690x over previous
//
#include <hip/hip_runtime.h>
#include <hip/hip_bf16.h>
#include <cstddef>

#define D_MODEL 1024
#define D_STATE 16
#define D_CONV 4
#define DT_RANK 64
#define D_INNER 2048
#define BB 2
#define LL 2048
#define TT (BB * LL)          // 4096 tokens
#define NSEG 64
#define SEGLEN (LL / NSEG)    // 32
#define NCHAN (BB * D_INNER)  // 4096

typedef __bf16 bf16x8 __attribute__((ext_vector_type(8)));
typedef float floatx4 __attribute__((ext_vector_type(4)));

__device__ __forceinline__ unsigned short f2bf(float f) {
  unsigned u = __float_as_uint(f);
  unsigned r = u + 0x7FFF + ((u >> 16) & 1);  // round-to-nearest-even
  return (unsigned short)(r >> 16);
}
__device__ __forceinline__ float b2f(unsigned short v) {
  return __uint_as_float((unsigned)v << 16);
}

// ---------------------------------------------------------------------------
// All four weight casts in one launch. Outputs are contiguous in ws.
// float4 sizes: in_proj 1048576, out_proj 524288, x_proj 49152, dt_proj 32768
// ---------------------------------------------------------------------------
__global__ __launch_bounds__(256) void cast_weights_kernel(
    const float* __restrict__ w0, const float* __restrict__ w1,
    const float* __restrict__ w2, const float* __restrict__ w3,
    unsigned short* __restrict__ dst) {
  int i = blockIdx.x * 256 + threadIdx.x;
  const float* src;
  int off;
  if (i < 1048576) { src = w0; off = 0; }
  else if (i < 1572864) { src = w1; off = 1048576; }
  else if (i < 1622016) { src = w2; off = 1572864; }
  else if (i < 1654784) { src = w3; off = 1622016; }
  else return;
  float4 v = reinterpret_cast<const float4*>(src)[i - off];
  ushort4 o;
  o.x = f2bf(v.x); o.y = f2bf(v.y); o.z = f2bf(v.z); o.w = f2bf(v.w);
  reinterpret_cast<ushort4*>(dst)[i] = o;
}

// Repack dt columns (0..63) of xd (row stride 96, fp32) into bf16 (stride 64)
__global__ __launch_bounds__(256) void cast_dt_kernel(
    const float* __restrict__ xd, unsigned short* __restrict__ dtA) {
  int i = blockIdx.x * 256 + threadIdx.x;  // 65536 total
  int row = i >> 4, c = (i & 15) * 4;
  float4 v = *reinterpret_cast<const float4*>(xd + (size_t)row * 96 + c);
  ushort4 o;
  o.x = f2bf(v.x); o.y = f2bf(v.y); o.z = f2bf(v.z); o.w = f2bf(v.w);
  *reinterpret_cast<ushort4*>(dtA + (size_t)row * 64 + c) = o;
}

// ---------------------------------------------------------------------------
// LayerNorm: one block per token, 256 threads; bf16 output.
// ---------------------------------------------------------------------------
__global__ __launch_bounds__(256) void layernorm_kernel(
    const float* __restrict__ x, const float* __restrict__ w,
    const float* __restrict__ b, unsigned short* __restrict__ xn) {
  int t = blockIdx.x;
  int tid = threadIdx.x;
  const float4* xr = reinterpret_cast<const float4*>(x + (size_t)t * D_MODEL);
  float4 xv = xr[tid];
  float s = xv.x + xv.y + xv.z + xv.w;
  float sq = xv.x * xv.x + xv.y * xv.y + xv.z * xv.z + xv.w * xv.w;
  for (int off = 32; off >= 1; off >>= 1) {
    s += __shfl_down(s, off);
    sq += __shfl_down(sq, off);
  }
  __shared__ float red[8];
  int wave = tid >> 6;
  if ((tid & 63) == 0) { red[wave * 2] = s; red[wave * 2 + 1] = sq; }
  __syncthreads();
  if (tid == 0) {
    float S = 0.f, Q = 0.f;
    for (int i = 0; i < 4; ++i) { S += red[2 * i]; Q += red[2 * i + 1]; }
    float mean = S * (1.f / D_MODEL);
    float var = Q * (1.f / D_MODEL) - mean * mean;
    red[0] = mean;
    red[1] = rsqrtf(var + 1e-5f);
  }
  __syncthreads();
  float mean = red[0], inv = red[1];
  const float4* wr = reinterpret_cast<const float4*>(w);
  const float4* br = reinterpret_cast<const float4*>(b);
  float4 wv = wr[tid], bv = br[tid];
  ushort4 o;
  o.x = f2bf((xv.x - mean) * inv * wv.x + bv.x);
  o.y = f2bf((xv.y - mean) * inv * wv.y + bv.y);
  o.z = f2bf((xv.z - mean) * inv * wv.z + bv.z);
  o.w = f2bf((xv.w - mean) * inv * wv.w + bv.w);
  reinterpret_cast<ushort4*>(xn + (size_t)t * D_MODEL)[tid] = o;
}

// ---------------------------------------------------------------------------
// bf16 MFMA NT GEMM: C[M,N] = A[M,K] * B[N,K]^T, A/B bf16 row-major.
// BM=128, BN=WNF*32 (64 or 128), BK=32; 4 waves, each 64 x (WNF*16).
// XCD-band swizzle: lid%8 -> XCD owns a gy/8-row band, walks columns, so the
// A band (~1-2MB) stays resident in that XCD's 4MB L2.
// kslice>1: blockIdx.z selects a K-slice, accumulate via atomicAdd (EPI 0).
// EPI 0: f32 (atomic if kslice>1); 1: softplus(v+bias[col]) -> bf16;
// EPI 2: v+resid -> f32; 4: in_proj dual (col<D_INNER: bf16 u to C;
//        col>=D_INNER: silu -> bf16 to C2).
// ---------------------------------------------------------------------------
template <int WNF, int EPI, typename OT>
__global__ __launch_bounds__(256) void gemm_bf16_kernel(
    const unsigned short* __restrict__ A, int lda,
    const unsigned short* __restrict__ B, int ldb,
    OT* __restrict__ C, int ldc, int M, int N, int K,
    const float* __restrict__ bias, const float* __restrict__ resid, int ldr,
    unsigned short* __restrict__ C2, int kslice) {
  constexpr int BN = WNF * 32;
  __shared__ unsigned short Atile[128 * 32];
  __shared__ unsigned short Btile[BN * 32];
  const int tid = threadIdx.x;
  const int lane = tid & 63;
  const int wv = tid >> 6;
  const int wrow = (wv >> 1) * 64;
  const int wcol = (wv & 1) * (WNF * 16);
  // XCD-band block swizzle (gy % 8 == 0 for all our launches)
  int gx = gridDim.x, gy = gridDim.y;
  int lid = blockIdx.y * gx + blockIdx.x;
  int rpx = gy >> 3;
  int xcd = lid & 7;
  int q = lid >> 3;
  int by = xcd * rpx + (q % rpx);
  int bx = q / rpx;
  const int row0 = by * 128;
  const int col0 = bx * BN;
  const int m = lane & 15;
  const int qq = lane >> 4;

  int k0lo = 0, k0hi = K;
  if (kslice > 1) {
    int ks = K / kslice;
    k0lo = blockIdx.z * ks;
    k0hi = k0lo + ks;
  }

  floatx4 acc[4][WNF] = {};

  for (int k0 = k0lo; k0 < k0hi; k0 += 32) {
#pragma unroll
    for (int t = 0; t < 2; ++t) {
      int slot = wv * 128 + t * 64 + lane;
      int row = slot >> 2;
      int kg = (slot & 3) ^ ((row >> 1) & 3);
      const unsigned short* ga = A + (size_t)(row0 + row) * lda + k0 + kg * 8;
      __builtin_amdgcn_global_load_lds(
          (const __attribute__((address_space(1))) void*)ga,
          (__attribute__((address_space(3))) void*)(Atile + slot * 8), 16, 0, 0);
    }
#pragma unroll
    for (int t = 0; t < BN / 64; ++t) {
      int slot = (BN == 128) ? (wv * 128 + t * 64 + lane) : tid;
      int row = slot >> 2;
      int kg = (slot & 3) ^ ((row >> 1) & 3);
      int rowB = col0 + row;
      if (rowB >= N) rowB = N - 1;  // clamp (x_proj N=96)
      const unsigned short* gb = B + (size_t)rowB * ldb + k0 + kg * 8;
      __builtin_amdgcn_global_load_lds(
          (const __attribute__((address_space(1))) void*)gb,
          (__attribute__((address_space(3))) void*)(Btile + slot * 8), 16, 0, 0);
    }
    __syncthreads();
    bf16x8 af[4], bfr[WNF];
#pragma unroll
    for (int i = 0; i < 4; ++i) {
      int ra = wrow + i * 16 + m;
      int sa = ra * 4 + (qq ^ ((ra >> 1) & 3));
      af[i] = *reinterpret_cast<const bf16x8*>(Atile + sa * 8);
    }
#pragma unroll
    for (int j = 0; j < WNF; ++j) {
      int rb = wcol + j * 16 + m;
      int sb = rb * 4 + (qq ^ ((rb >> 1) & 3));
      bfr[j] = *reinterpret_cast<const bf16x8*>(Btile + sb * 8);
    }
#pragma unroll
    for (int i = 0; i < 4; ++i)
#pragma unroll
      for (int j = 0; j < WNF; ++j)
        acc[i][j] = __builtin_amdgcn_mfma_f32_16x16x32_bf16(
            af[i], bfr[j], acc[i][j], 0, 0, 0);
    __syncthreads();
  }

  // epilogue: C/D layout col = m, row = qq*4 + r
#pragma unroll
  for (int j = 0; j < WNF; ++j) {
    int gc = col0 + wcol + j * 16 + m;
    if (gc >= N) continue;
#pragma unroll
    for (int i = 0; i < 4; ++i) {
#pragma unroll
      for (int r = 0; r < 4; ++r) {
        int gr = row0 + wrow + i * 16 + qq * 4 + r;
        float v = acc[i][j][r];
        if (EPI == 1) {
          float xv = v + bias[gc];
          float sp = fmaxf(xv, 0.f) + log1pf(expf(-fabsf(xv)));
          ((unsigned short*)C)[(size_t)gr * ldc + gc] = f2bf(sp);
        } else if (EPI == 2) {
          ((float*)C)[(size_t)gr * ldc + gc] = v + resid[(size_t)gr * ldr + gc];
        } else if (EPI == 4) {
          if (gc >= D_INNER) {
            float sv = v / (1.f + expf(-v));
            C2[(size_t)gr * D_INNER + (gc - D_INNER)] = f2bf(sv);
          } else {
            ((unsigned short*)C)[(size_t)gr * ldc + gc] = f2bf(v);
          }
        } else {
          if (kslice > 1)
            atomicAdd(&((float*)C)[(size_t)gr * ldc + gc], v);
          else
            ((float*)C)[(size_t)gr * ldc + gc] = v;
        }
      }
    }
  }
}

// ---------------------------------------------------------------------------
// Depthwise causal conv (width 4) + SiLU; bf16 in, bf16 out.
// ---------------------------------------------------------------------------
__global__ __launch_bounds__(256) void conv_silu_kernel(
    const unsigned short* __restrict__ ub, const float* __restrict__ cw,
    const float* __restrict__ cb, unsigned short* __restrict__ ucb) {
  size_t idx = (size_t)blockIdx.x * 256 + threadIdx.x;
  if (idx >= (size_t)TT * D_INNER) return;
  int d = (int)(idx & (D_INNER - 1));
  int t = (int)(idx >> 11);
  int l = t & (LL - 1);
  float acc = cb[d];
#pragma unroll
  for (int k = 0; k < D_CONV; ++k) {
    int ll = l - (D_CONV - 1) + k;
    if (ll >= 0)
      acc += b2f(ub[idx - (size_t)(D_CONV - 1 - k) * D_INNER]) * cw[d * D_CONV + k];
  }
  ucb[idx] = f2bf(acc / (1.f + expf(-acc)));  // SiLU
}

// ---------------------------------------------------------------------------
// Segmented selective scan, channel-per-thread (h[16] in VGPRs). delta bf16.
// ---------------------------------------------------------------------------
__global__ __launch_bounds__(256) void scan_partial_kernel(
    const unsigned short* __restrict__ deltab, const unsigned short* __restrict__ ucb,
    const float* __restrict__ xd, const float* __restrict__ A_log,
    float* __restrict__ aprod_buf, float* __restrict__ hend_buf) {
  __shared__ float Bs[SEGLEN][16];
  const int tid = threadIdx.x;
  const int d = blockIdx.x * 256 + tid;
  const int s = blockIdx.y;
  const int b = blockIdx.z;
  const int chan = b * D_INNER + d;
  const size_t tbase = (size_t)b * LL + (size_t)s * SEGLEN;

  {
    int row = tid >> 3, pair = tid & 7;
    *reinterpret_cast<float2*>(&Bs[row][pair * 2]) =
        *reinterpret_cast<const float2*>(xd + (tbase + row) * 96 + 64 + pair * 2);
  }
  floatx4 Ac[4];
  {
    const floatx4* ar = reinterpret_cast<const floatx4*>(A_log + (size_t)d * D_STATE);
#pragma unroll
    for (int k = 0; k < 4; ++k) {
      floatx4 v = ar[k];
      for (int j = 0; j < 4; ++j) Ac[k][j] = -__expf(v[j]) * 1.4426950408889634f;
    }
  }
  __syncthreads();

  floatx4 h[4] = {};
  float S = 0.f;
  for (int l = 0; l < SEGLEN; ++l) {
    size_t t = tbase + l;
    float dl = b2f(deltab[t * D_INNER + d]);
    float ul = b2f(ucb[t * D_INNER + d]);
    float dlul = dl * ul;
    S += dl;
#pragma unroll
    for (int k = 0; k < 4; ++k) {
      floatx4 bv = *reinterpret_cast<const floatx4*>(&Bs[l][k * 4]);
      floatx4 a;
      for (int j = 0; j < 4; ++j) a[j] = __builtin_amdgcn_exp2f(dl * Ac[k][j]);
      h[k] = a * h[k] + dlul * bv;
    }
  }
  size_t base = ((size_t)s * NCHAN + chan) * D_STATE;
#pragma unroll
  for (int k = 0; k < 4; ++k) {
    floatx4 ap;
    for (int j = 0; j < 4; ++j) ap[j] = __builtin_amdgcn_exp2f(S * Ac[k][j]);
    *reinterpret_cast<floatx4*>(hend_buf + base + k * 4) = h[k];
    *reinterpret_cast<floatx4*>(aprod_buf + base + k * 4) = ap;
  }
}

__global__ __launch_bounds__(256) void scan_combine_kernel(
    float* __restrict__ aprod_buf, const float* __restrict__ hend_buf) {
  int idx = blockIdx.x * 256 + threadIdx.x;  // chan*16 + n, 65536 total
  float H = 0.f;
  for (int s = 0; s < NSEG; ++s) {
    size_t si = (size_t)s * (NCHAN * D_STATE) + idx;
    float a = aprod_buf[si];
    float he = hend_buf[si];
    aprod_buf[si] = H;  // h_start for segment s
    H = he + a * H;
  }
}

__global__ __launch_bounds__(256) void scan_final_kernel(
    const unsigned short* __restrict__ deltab, const unsigned short* __restrict__ ucb,
    const float* __restrict__ xd, const unsigned short* __restrict__ zsb,
    const float* __restrict__ A_log, const float* __restrict__ Dv,
    const float* __restrict__ hstart_buf, unsigned short* __restrict__ yb) {
  __shared__ float BCs[SEGLEN][32];
  const int tid = threadIdx.x;
  const int d = blockIdx.x * 256 + tid;
  const int s = blockIdx.y;
  const int b = blockIdx.z;
  const int chan = b * D_INNER + d;
  const size_t tbase = (size_t)b * LL + (size_t)s * SEGLEN;

  {
    int row = tid >> 3, quad = tid & 7;
    *reinterpret_cast<float4*>(&BCs[row][quad * 4]) =
        *reinterpret_cast<const float4*>(xd + (tbase + row) * 96 + 64 + quad * 4);
  }
  floatx4 Ac[4];
  {
    const floatx4* ar = reinterpret_cast<const floatx4*>(A_log + (size_t)d * D_STATE);
#pragma unroll
    for (int k = 0; k < 4; ++k) {
      floatx4 v = ar[k];
      for (int j = 0; j < 4; ++j) Ac[k][j] = -__expf(v[j]) * 1.4426950408889634f;
    }
  }
  float Dd = Dv[d];
  floatx4 h[4];
  {
    size_t base = ((size_t)s * NCHAN + chan) * D_STATE;
#pragma unroll
    for (int k = 0; k < 4; ++k)
      h[k] = *reinterpret_cast<const floatx4*>(hstart_buf + base + k * 4);
  }
  __syncthreads();

  for (int l = 0; l < SEGLEN; ++l) {
    size_t t = tbase + l;
    float dl = b2f(deltab[t * D_INNER + d]);
    float ul = b2f(ucb[t * D_INNER + d]);
    float dlul = dl * ul;
    floatx4 psum = {};
#pragma unroll
    for (int k = 0; k < 4; ++k) {
      floatx4 bv = *reinterpret_cast<const floatx4*>(&BCs[l][k * 4]);
      floatx4 cv = *reinterpret_cast<const floatx4*>(&BCs[l][16 + k * 4]);
      floatx4 a;
      for (int j = 0; j < 4; ++j) a[j] = __builtin_amdgcn_exp2f(dl * Ac[k][j]);
      h[k] = a * h[k] + dlul * bv;
      psum += h[k] * cv;
    }
    float p = psum[0] + psum[1] + psum[2] + psum[3];
    float zs = b2f(zsb[t * D_INNER + d]);
    yb[t * D_INNER + d] = f2bf((p + ul * Dd) * zs);  // in-place over ucb: safe
  }
}

// ---------------------------------------------------------------------------
extern "C" void kernel_launch(void* const* d_in, const int* in_sizes, int n_in,
                              void* d_out, int out_size, void* d_ws, size_t ws_size,
                              hipStream_t stream) {
  const float* x         = (const float*)d_in[0];
  const float* ln_w      = (const float*)d_in[1];
  const float* ln_b      = (const float*)d_in[2];
  const float* in_proj_w = (const float*)d_in[3];
  const float* conv_w    = (const float*)d_in[4];
  const float* conv_b    = (const float*)d_in[5];
  const float* x_proj_w  = (const float*)d_in[6];
  const float* dt_proj_w = (const float*)d_in[7];
  const float* dt_proj_b = (const float*)d_in[8];
  const float* A_log     = (const float*)d_in[9];
  const float* Dvec      = (const float*)d_in[10];
  const float* out_proj_w= (const float*)d_in[11];
  float* out = (float*)d_out;

  // workspace layout (all segment sizes multiples of 8 ushorts -> 16B aligned)
  unsigned short* wip = (unsigned short*)d_ws;            // 4194304
  unsigned short* wop = wip + 4194304;                    // 2097152
  unsigned short* wxp = wop + 2097152;                    // 196608
  unsigned short* wdt = wxp + 196608;                     // 131072
  unsigned short* xnb = wdt + 131072;                     // T*1024
  unsigned short* ub  = xnb + (size_t)TT * D_MODEL;       // T*2048 (u bf16)
  unsigned short* ucb = ub + (size_t)TT * D_INNER;        // T*2048 (conv out -> y)
  unsigned short* zsb = ucb + (size_t)TT * D_INNER;       // T*2048 (silu(z))
  unsigned short* dtA = zsb + (size_t)TT * D_INNER;       // T*64
  unsigned short* deltab = dtA + (size_t)TT * DT_RANK;    // T*2048 (delta bf16)
  float* xd    = (float*)(deltab + (size_t)TT * D_INNER); // T*96 f32
  float* hend  = xd + (size_t)TT * 96;                    // NSEG*NCHAN*16
  float* aprod = hend + (size_t)NSEG * NCHAN * D_STATE;   // NSEG*NCHAN*16

  // 0. weight casts (one launch) + zero xd for split-K atomics
  cast_weights_kernel<<<6464, 256, 0, stream>>>(in_proj_w, out_proj_w,
                                                x_proj_w, dt_proj_w, wip);
  hipMemsetAsync(xd, 0, (size_t)TT * 96 * sizeof(float), stream);

  // 1. LayerNorm -> bf16
  layernorm_kernel<<<TT, 256, 0, stream>>>(x, ln_w, ln_b, xnb);

  // 2. fused in_proj -> u bf16 (cols<2048), silu(z) bf16 (cols>=2048)
  gemm_bf16_kernel<4, 4, unsigned short><<<dim3(32, 32), 256, 0, stream>>>(
      xnb, D_MODEL, wip, D_MODEL, ub, D_INNER, TT, 2 * D_INNER, D_MODEL,
      nullptr, nullptr, 0, zsb, 1);

  // 3. causal depthwise conv + SiLU -> bf16
  conv_silu_kernel<<<(TT * D_INNER) / 256, 256, 0, stream>>>(ub, conv_w, conv_b, ucb);

  // 4. x_proj -> xd f32 (N=96), BN=64, split-K=4 with atomics
  gemm_bf16_kernel<2, 0, float><<<dim3(2, 32, 4), 256, 0, stream>>>(
      ucb, D_INNER, wxp, D_INNER, xd, 96, TT, 96, D_INNER,
      nullptr, nullptr, 0, nullptr, 4);

  // 5. dt repack + dt_proj + softplus -> delta bf16
  cast_dt_kernel<<<(TT * DT_RANK / 4) / 256, 256, 0, stream>>>(xd, dtA);
  gemm_bf16_kernel<4, 1, unsigned short><<<dim3(16, 32), 256, 0, stream>>>(
      dtA, DT_RANK, wdt, DT_RANK, deltab, D_INNER, TT, D_INNER, DT_RANK,
      dt_proj_b, nullptr, 0, nullptr, 1);

  // 6. segmented selective scan + gate -> y bf16 (in ucb)
  scan_partial_kernel<<<dim3(D_INNER / 256, NSEG, BB), 256, 0, stream>>>(
      deltab, ucb, xd, A_log, aprod, hend);
  scan_combine_kernel<<<(NCHAN * D_STATE) / 256, 256, 0, stream>>>(aprod, hend);
  scan_final_kernel<<<dim3(D_INNER / 256, NSEG, BB), 256, 0, stream>>>(
      deltab, ucb, xd, zsb, A_log, Dvec, aprod, ucb);

  // 7. out_proj + residual (BN=64 -> 512 blocks)
  gemm_bf16_kernel<2, 2, float><<<dim3(16, 32), 256, 0, stream>>>(
      ucb, D_INNER, wop, D_INNER, out, D_MODEL, TT, D_MODEL, D_INNER,
      nullptr, x, D_MODEL, nullptr, 1);
}

// Round 6
// 362.875 us; speedup vs baseline: 9.1966x; 1.0522x over previous
//
#include <hip/hip_runtime.h>
#include <hip/hip_bf16.h>
#include <cstddef>

#define D_MODEL 1024
#define D_STATE 16
#define D_CONV 4
#define DT_RANK 64
#define D_INNER 2048
#define BB 2
#define LL 2048
#define TT (BB * LL)          // 4096 tokens
#define NSEG 64
#define SEGLEN (LL / NSEG)    // 32
#define NCHAN (BB * D_INNER)  // 4096

typedef __bf16 bf16x8 __attribute__((ext_vector_type(8)));
typedef float floatx4 __attribute__((ext_vector_type(4)));
typedef unsigned short ushortx8 __attribute__((ext_vector_type(8)));

__device__ __forceinline__ unsigned short f2bf(float f) {
  unsigned u = __float_as_uint(f);
  unsigned r = u + 0x7FFF + ((u >> 16) & 1);  // round-to-nearest-even
  return (unsigned short)(r >> 16);
}
__device__ __forceinline__ float b2f(unsigned short v) {
  return __uint_as_float((unsigned)v << 16);
}

// ---------------------------------------------------------------------------
// All four weight casts in one launch.
// ---------------------------------------------------------------------------
__global__ __launch_bounds__(256) void cast_weights_kernel(
    const float* __restrict__ w0, const float* __restrict__ w1,
    const float* __restrict__ w2, const float* __restrict__ w3,
    unsigned short* __restrict__ dst) {
  int i = blockIdx.x * 256 + threadIdx.x;
  const float* src;
  int off;
  if (i < 1048576) { src = w0; off = 0; }
  else if (i < 1572864) { src = w1; off = 1048576; }
  else if (i < 1622016) { src = w2; off = 1572864; }
  else if (i < 1654784) { src = w3; off = 1622016; }
  else return;
  float4 v = reinterpret_cast<const float4*>(src)[i - off];
  ushort4 o;
  o.x = f2bf(v.x); o.y = f2bf(v.y); o.z = f2bf(v.z); o.w = f2bf(v.w);
  reinterpret_cast<ushort4*>(dst)[i] = o;
}

// Repack dt columns (0..63) of xd (row stride 96, fp32) into bf16 (stride 64)
__global__ __launch_bounds__(256) void cast_dt_kernel(
    const float* __restrict__ xd, unsigned short* __restrict__ dtA) {
  int i = blockIdx.x * 256 + threadIdx.x;  // 65536 total
  int row = i >> 4, c = (i & 15) * 4;
  float4 v = *reinterpret_cast<const float4*>(xd + (size_t)row * 96 + c);
  ushort4 o;
  o.x = f2bf(v.x); o.y = f2bf(v.y); o.z = f2bf(v.z); o.w = f2bf(v.w);
  *reinterpret_cast<ushort4*>(dtA + (size_t)row * 64 + c) = o;
}

// ---------------------------------------------------------------------------
// LayerNorm: one block per token, 256 threads; bf16 output.
// ---------------------------------------------------------------------------
__global__ __launch_bounds__(256) void layernorm_kernel(
    const float* __restrict__ x, const float* __restrict__ w,
    const float* __restrict__ b, unsigned short* __restrict__ xn) {
  int t = blockIdx.x;
  int tid = threadIdx.x;
  const float4* xr = reinterpret_cast<const float4*>(x + (size_t)t * D_MODEL);
  float4 xv = xr[tid];
  float s = xv.x + xv.y + xv.z + xv.w;
  float sq = xv.x * xv.x + xv.y * xv.y + xv.z * xv.z + xv.w * xv.w;
  for (int off = 32; off >= 1; off >>= 1) {
    s += __shfl_down(s, off);
    sq += __shfl_down(sq, off);
  }
  __shared__ float red[8];
  int wave = tid >> 6;
  if ((tid & 63) == 0) { red[wave * 2] = s; red[wave * 2 + 1] = sq; }
  __syncthreads();
  if (tid == 0) {
    float S = 0.f, Q = 0.f;
    for (int i = 0; i < 4; ++i) { S += red[2 * i]; Q += red[2 * i + 1]; }
    float mean = S * (1.f / D_MODEL);
    float var = Q * (1.f / D_MODEL) - mean * mean;
    red[0] = mean;
    red[1] = rsqrtf(var + 1e-5f);
  }
  __syncthreads();
  float mean = red[0], inv = red[1];
  const float4* wr = reinterpret_cast<const float4*>(w);
  const float4* br = reinterpret_cast<const float4*>(b);
  float4 wv = wr[tid], bv = br[tid];
  ushort4 o;
  o.x = f2bf((xv.x - mean) * inv * wv.x + bv.x);
  o.y = f2bf((xv.y - mean) * inv * wv.y + bv.y);
  o.z = f2bf((xv.z - mean) * inv * wv.z + bv.z);
  o.w = f2bf((xv.w - mean) * inv * wv.w + bv.w);
  reinterpret_cast<ushort4*>(xn + (size_t)t * D_MODEL)[tid] = o;
}

// ---------------------------------------------------------------------------
// bf16 MFMA NT GEMM: C[M,N] = A[M,K] * B[N,K]^T, A/B bf16 row-major.
// BM=128, BN=WNF*32, BK=64 (2 k-steps, 32 MFMA per barrier pair).
// LDS layout: row-major [row][kg] with kg XOR-swizzled by (row&7); 16B/slot.
// XCD-band swizzle for L2 locality. kslice>1: K-sliced atomic f32 accumulate.
// EPI 0: f32 (atomic if kslice>1); 1: softplus(v+bias[col]) -> bf16 via LDS;
// EPI 2: v+resid -> f32; 4: in_proj dual bf16 via LDS (block col half picks
//        u plain vs silu->C2).
// ---------------------------------------------------------------------------
template <int WNF, int EPI, typename OT>
__global__ __launch_bounds__(256) void gemm_bf16_kernel(
    const unsigned short* __restrict__ A, int lda,
    const unsigned short* __restrict__ B, int ldb,
    OT* __restrict__ C, int ldc, int M, int N, int K,
    const float* __restrict__ bias, const float* __restrict__ resid, int ldr,
    unsigned short* __restrict__ C2, int kslice) {
  constexpr int BN = WNF * 32;
  constexpr int BSLOTS = BN * 8;            // 16B slots in B tile
  constexpr bool NEEDSTAGE = (EPI == 1 || EPI == 4);
  constexpr int TILE_USH = 8192 + BN * 64;  // Atile + Btile in ushorts
  constexpr int SMEM_USH = NEEDSTAGE && (4 * 64 * 66 > TILE_USH)
                               ? 4 * 64 * 66 : TILE_USH;
  __shared__ unsigned short sm[SMEM_USH];
  unsigned short* Atile = sm;
  unsigned short* Btile = sm + 8192;

  const int tid = threadIdx.x;
  const int lane = tid & 63;
  const int wv = tid >> 6;
  const int wrow = (wv >> 1) * 64;
  const int wcol = (wv & 1) * (WNF * 16);
  // XCD-band block swizzle (gy == 32 for all launches)
  int gx = gridDim.x, gy = gridDim.y;
  int lid = blockIdx.y * gx + blockIdx.x;
  int rpx = gy >> 3;
  int xcd = lid & 7;
  int qq0 = lid >> 3;
  int by = xcd * rpx + (qq0 % rpx);
  int bx = qq0 / rpx;
  const int row0 = by * 128;
  const int col0 = bx * BN;
  const int m = lane & 15;
  const int q = lane >> 4;

  int k0lo = 0, k0hi = K;
  if (kslice > 1) {
    int ks = K / kslice;
    k0lo = blockIdx.z * ks;
    k0hi = k0lo + ks;
  }

  floatx4 acc[4][WNF] = {};

  for (int k0 = k0lo; k0 < k0hi; k0 += 64) {
#pragma unroll
    for (int t = 0; t < 4; ++t) {
      int slot = wv * 256 + t * 64 + lane;
      int row = slot >> 3;
      int kg = (slot & 7) ^ (row & 7);
      const unsigned short* ga = A + (size_t)(row0 + row) * lda + k0 + kg * 8;
      __builtin_amdgcn_global_load_lds(
          (const __attribute__((address_space(1))) void*)ga,
          (__attribute__((address_space(3))) void*)(Atile + slot * 8), 16, 0, 0);
    }
#pragma unroll
    for (int t = 0; t < BSLOTS / 256; ++t) {
      int slot = t * 256 + tid;
      int row = slot >> 3;
      int kg = (slot & 7) ^ (row & 7);
      int rowB = col0 + row;
      if (rowB >= N) rowB = N - 1;  // clamp (x_proj N=96)
      const unsigned short* gb = B + (size_t)rowB * ldb + k0 + kg * 8;
      __builtin_amdgcn_global_load_lds(
          (const __attribute__((address_space(1))) void*)gb,
          (__attribute__((address_space(3))) void*)(Btile + slot * 8), 16, 0, 0);
    }
    __syncthreads();
#pragma unroll
    for (int s = 0; s < 2; ++s) {
      int xr = ((s * 4 + q) ^ (m & 7)) * 8;
      bf16x8 af[4], bfr[WNF];
#pragma unroll
      for (int i = 0; i < 4; ++i)
        af[i] = *reinterpret_cast<const bf16x8*>(
            Atile + (wrow + i * 16 + m) * 64 + xr);
#pragma unroll
      for (int j = 0; j < WNF; ++j)
        bfr[j] = *reinterpret_cast<const bf16x8*>(
            Btile + (wcol + j * 16 + m) * 64 + xr);
#pragma unroll
      for (int i = 0; i < 4; ++i)
#pragma unroll
        for (int j = 0; j < WNF; ++j)
          acc[i][j] = __builtin_amdgcn_mfma_f32_16x16x32_bf16(
              af[i], bfr[j], acc[i][j], 0, 0, 0);
    }
    __syncthreads();
  }

  if (NEEDSTAGE) {
    // bf16 outputs: pack via LDS (row stride 66 breaks bank alignment), then
    // 16B coalesced stores (full 128B-line coverage per wave row).
    unsigned short* st = sm + wv * 4224;  // 64*66
    const bool zhalf = (EPI == 4) && (col0 >= D_INNER);
#pragma unroll
    for (int i = 0; i < 4; ++i)
#pragma unroll
      for (int j = 0; j < WNF; ++j)
#pragma unroll
        for (int r = 0; r < 4; ++r) {
          float v = acc[i][j][r];
          if (EPI == 1) {
            float xv = v + bias[col0 + wcol + j * 16 + m];
            v = fmaxf(xv, 0.f) + log1pf(expf(-fabsf(xv)));
          } else if (zhalf) {
            v = v / (1.f + expf(-v));
          }
          st[(i * 16 + q * 4 + r) * 66 + j * 16 + m] = f2bf(v);
        }
    __syncthreads();
    unsigned short* Cb;
    int cb;
    if (EPI == 4 && col0 >= D_INNER) { Cb = C2; cb = col0 - D_INNER + wcol; }
    else { Cb = (unsigned short*)C; cb = col0 + wcol; }
    constexpr int LPR = WNF * 2;   // lanes per row (8 ushorts each)
    constexpr int RPI = 64 / LPR;  // rows per instruction
#pragma unroll
    for (int t = 0; t < 64 / RPI; ++t) {
      int r = t * RPI + lane / LPR;
      int co = (lane % LPR) * 8;
      ushortx8 val = *reinterpret_cast<const ushortx8*>(st + r * 66 + co);
      *reinterpret_cast<ushortx8*>(
          Cb + (size_t)(row0 + wrow + r) * ldc + cb + co) = val;
    }
  } else {
    // f32 epilogue (EPI 0 / 2)
#pragma unroll
    for (int j = 0; j < WNF; ++j) {
      int gc = col0 + wcol + j * 16 + m;
      if (gc >= N) continue;
#pragma unroll
      for (int i = 0; i < 4; ++i) {
#pragma unroll
        for (int r = 0; r < 4; ++r) {
          int gr = row0 + wrow + i * 16 + q * 4 + r;
          float v = acc[i][j][r];
          if (EPI == 2) {
            ((float*)C)[(size_t)gr * ldc + gc] = v + resid[(size_t)gr * ldr + gc];
          } else {
            if (kslice > 1)
              atomicAdd(&((float*)C)[(size_t)gr * ldc + gc], v);
            else
              ((float*)C)[(size_t)gr * ldc + gc] = v;
          }
        }
      }
    }
  }
}

// ---------------------------------------------------------------------------
// Depthwise causal conv (width 4) + SiLU; bf16 in, bf16 out.
// ---------------------------------------------------------------------------
__global__ __launch_bounds__(256) void conv_silu_kernel(
    const unsigned short* __restrict__ ub, const float* __restrict__ cw,
    const float* __restrict__ cb, unsigned short* __restrict__ ucb) {
  size_t idx = (size_t)blockIdx.x * 256 + threadIdx.x;
  if (idx >= (size_t)TT * D_INNER) return;
  int d = (int)(idx & (D_INNER - 1));
  int t = (int)(idx >> 11);
  int l = t & (LL - 1);
  float acc = cb[d];
#pragma unroll
  for (int k = 0; k < D_CONV; ++k) {
    int ll = l - (D_CONV - 1) + k;
    if (ll >= 0)
      acc += b2f(ub[idx - (size_t)(D_CONV - 1 - k) * D_INNER]) * cw[d * D_CONV + k];
  }
  ucb[idx] = f2bf(acc / (1.f + expf(-acc)));  // SiLU
}

// ---------------------------------------------------------------------------
// Segmented selective scan, channel-per-thread (h[16] in VGPRs). delta bf16.
// ---------------------------------------------------------------------------
__global__ __launch_bounds__(256) void scan_partial_kernel(
    const unsigned short* __restrict__ deltab, const unsigned short* __restrict__ ucb,
    const float* __restrict__ xd, const float* __restrict__ A_log,
    float* __restrict__ aprod_buf, float* __restrict__ hend_buf) {
  __shared__ float Bs[SEGLEN][16];
  const int tid = threadIdx.x;
  const int d = blockIdx.x * 256 + tid;
  const int s = blockIdx.y;
  const int b = blockIdx.z;
  const int chan = b * D_INNER + d;
  const size_t tbase = (size_t)b * LL + (size_t)s * SEGLEN;

  {
    int row = tid >> 3, pair = tid & 7;
    *reinterpret_cast<float2*>(&Bs[row][pair * 2]) =
        *reinterpret_cast<const float2*>(xd + (tbase + row) * 96 + 64 + pair * 2);
  }
  floatx4 Ac[4];
  {
    const floatx4* ar = reinterpret_cast<const floatx4*>(A_log + (size_t)d * D_STATE);
#pragma unroll
    for (int k = 0; k < 4; ++k) {
      floatx4 v = ar[k];
      for (int j = 0; j < 4; ++j) Ac[k][j] = -__expf(v[j]) * 1.4426950408889634f;
    }
  }
  __syncthreads();

  floatx4 h[4] = {};
  float S = 0.f;
  for (int l = 0; l < SEGLEN; ++l) {
    size_t t = tbase + l;
    float dl = b2f(deltab[t * D_INNER + d]);
    float ul = b2f(ucb[t * D_INNER + d]);
    float dlul = dl * ul;
    S += dl;
#pragma unroll
    for (int k = 0; k < 4; ++k) {
      floatx4 bv = *reinterpret_cast<const floatx4*>(&Bs[l][k * 4]);
      floatx4 a;
      for (int j = 0; j < 4; ++j) a[j] = __builtin_amdgcn_exp2f(dl * Ac[k][j]);
      h[k] = a * h[k] + dlul * bv;
    }
  }
  size_t base = ((size_t)s * NCHAN + chan) * D_STATE;
#pragma unroll
  for (int k = 0; k < 4; ++k) {
    floatx4 ap;
    for (int j = 0; j < 4; ++j) ap[j] = __builtin_amdgcn_exp2f(S * Ac[k][j]);
    *reinterpret_cast<floatx4*>(hend_buf + base + k * 4) = h[k];
    *reinterpret_cast<floatx4*>(aprod_buf + base + k * 4) = ap;
  }
}

__global__ __launch_bounds__(256) void scan_combine_kernel(
    float* __restrict__ aprod_buf, const float* __restrict__ hend_buf) {
  int idx = blockIdx.x * 256 + threadIdx.x;  // chan*16 + n, 65536 total
  float H = 0.f;
  for (int s = 0; s < NSEG; ++s) {
    size_t si = (size_t)s * (NCHAN * D_STATE) + idx;
    float a = aprod_buf[si];
    float he = hend_buf[si];
    aprod_buf[si] = H;  // h_start for segment s
    H = he + a * H;
  }
}

__global__ __launch_bounds__(256) void scan_final_kernel(
    const unsigned short* __restrict__ deltab, const unsigned short* __restrict__ ucb,
    const float* __restrict__ xd, const unsigned short* __restrict__ zsb,
    const float* __restrict__ A_log, const float* __restrict__ Dv,
    const float* __restrict__ hstart_buf, unsigned short* __restrict__ yb) {
  __shared__ float BCs[SEGLEN][32];
  const int tid = threadIdx.x;
  const int d = blockIdx.x * 256 + tid;
  const int s = blockIdx.y;
  const int b = blockIdx.z;
  const int chan = b * D_INNER + d;
  const size_t tbase = (size_t)b * LL + (size_t)s * SEGLEN;

  {
    int row = tid >> 3, quad = tid & 7;
    *reinterpret_cast<float4*>(&BCs[row][quad * 4]) =
        *reinterpret_cast<const float4*>(xd + (tbase + row) * 96 + 64 + quad * 4);
  }
  floatx4 Ac[4];
  {
    const floatx4* ar = reinterpret_cast<const floatx4*>(A_log + (size_t)d * D_STATE);
#pragma unroll
    for (int k = 0; k < 4; ++k) {
      floatx4 v = ar[k];
      for (int j = 0; j < 4; ++j) Ac[k][j] = -__expf(v[j]) * 1.4426950408889634f;
    }
  }
  float Dd = Dv[d];
  floatx4 h[4];
  {
    size_t base = ((size_t)s * NCHAN + chan) * D_STATE;
#pragma unroll
    for (int k = 0; k < 4; ++k)
      h[k] = *reinterpret_cast<const floatx4*>(hstart_buf + base + k * 4);
  }
  __syncthreads();

  for (int l = 0; l < SEGLEN; ++l) {
    size_t t = tbase + l;
    float dl = b2f(deltab[t * D_INNER + d]);
    float ul = b2f(ucb[t * D_INNER + d]);
    float dlul = dl * ul;
    floatx4 psum = {};
#pragma unroll
    for (int k = 0; k < 4; ++k) {
      floatx4 bv = *reinterpret_cast<const floatx4*>(&BCs[l][k * 4]);
      floatx4 cv = *reinterpret_cast<const floatx4*>(&BCs[l][16 + k * 4]);
      floatx4 a;
      for (int j = 0; j < 4; ++j) a[j] = __builtin_amdgcn_exp2f(dl * Ac[k][j]);
      h[k] = a * h[k] + dlul * bv;
      psum += h[k] * cv;
    }
    float p = psum[0] + psum[1] + psum[2] + psum[3];
    float zs = b2f(zsb[t * D_INNER + d]);
    yb[t * D_INNER + d] = f2bf((p + ul * Dd) * zs);  // in-place over ucb: safe
  }
}

// ---------------------------------------------------------------------------
extern "C" void kernel_launch(void* const* d_in, const int* in_sizes, int n_in,
                              void* d_out, int out_size, void* d_ws, size_t ws_size,
                              hipStream_t stream) {
  const float* x         = (const float*)d_in[0];
  const float* ln_w      = (const float*)d_in[1];
  const float* ln_b      = (const float*)d_in[2];
  const float* in_proj_w = (const float*)d_in[3];
  const float* conv_w    = (const float*)d_in[4];
  const float* conv_b    = (const float*)d_in[5];
  const float* x_proj_w  = (const float*)d_in[6];
  const float* dt_proj_w = (const float*)d_in[7];
  const float* dt_proj_b = (const float*)d_in[8];
  const float* A_log     = (const float*)d_in[9];
  const float* Dvec      = (const float*)d_in[10];
  const float* out_proj_w= (const float*)d_in[11];
  float* out = (float*)d_out;

  // workspace layout (all segment sizes multiples of 8 ushorts -> 16B aligned)
  unsigned short* wip = (unsigned short*)d_ws;            // 4194304
  unsigned short* wop = wip + 4194304;                    // 2097152
  unsigned short* wxp = wop + 2097152;                    // 196608
  unsigned short* wdt = wxp + 196608;                     // 131072
  unsigned short* xnb = wdt + 131072;                     // T*1024
  unsigned short* ub  = xnb + (size_t)TT * D_MODEL;       // T*2048 (u bf16)
  unsigned short* ucb = ub + (size_t)TT * D_INNER;        // T*2048 (conv out -> y)
  unsigned short* zsb = ucb + (size_t)TT * D_INNER;       // T*2048 (silu(z))
  unsigned short* dtA = zsb + (size_t)TT * D_INNER;       // T*64
  unsigned short* deltab = dtA + (size_t)TT * DT_RANK;    // T*2048 (delta bf16)
  float* xd    = (float*)(deltab + (size_t)TT * D_INNER); // T*96 f32
  float* hend  = xd + (size_t)TT * 96;                    // NSEG*NCHAN*16
  float* aprod = hend + (size_t)NSEG * NCHAN * D_STATE;   // NSEG*NCHAN*16

  // 0. weight casts (one launch) + zero xd for split-K atomics
  cast_weights_kernel<<<6464, 256, 0, stream>>>(in_proj_w, out_proj_w,
                                                x_proj_w, dt_proj_w, wip);
  hipMemsetAsync(xd, 0, (size_t)TT * 96 * sizeof(float), stream);

  // 1. LayerNorm -> bf16
  layernorm_kernel<<<TT, 256, 0, stream>>>(x, ln_w, ln_b, xnb);

  // 2. fused in_proj -> u bf16 (cols<2048), silu(z) bf16 (cols>=2048)
  gemm_bf16_kernel<4, 4, unsigned short><<<dim3(32, 32), 256, 0, stream>>>(
      xnb, D_MODEL, wip, D_MODEL, ub, D_INNER, TT, 2 * D_INNER, D_MODEL,
      nullptr, nullptr, 0, zsb, 1);

  // 3. causal depthwise conv + SiLU -> bf16
  conv_silu_kernel<<<(TT * D_INNER) / 256, 256, 0, stream>>>(ub, conv_w, conv_b, ucb);

  // 4. x_proj -> xd f32 (N=96), BN=64, split-K=4 with atomics
  gemm_bf16_kernel<2, 0, float><<<dim3(2, 32, 4), 256, 0, stream>>>(
      ucb, D_INNER, wxp, D_INNER, xd, 96, TT, 96, D_INNER,
      nullptr, nullptr, 0, nullptr, 4);

  // 5. dt repack + dt_proj + softplus -> delta bf16 (single K-iteration)
  cast_dt_kernel<<<(TT * DT_RANK / 4) / 256, 256, 0, stream>>>(xd, dtA);
  gemm_bf16_kernel<4, 1, unsigned short><<<dim3(16, 32), 256, 0, stream>>>(
      dtA, DT_RANK, wdt, DT_RANK, deltab, D_INNER, TT, D_INNER, DT_RANK,
      dt_proj_b, nullptr, 0, nullptr, 1);

  // 6. segmented selective scan + gate -> y bf16 (in ucb)
  scan_partial_kernel<<<dim3(D_INNER / 256, NSEG, BB), 256, 0, stream>>>(
      deltab, ucb, xd, A_log, aprod, hend);
  scan_combine_kernel<<<(NCHAN * D_STATE) / 256, 256, 0, stream>>>(aprod, hend);
  scan_final_kernel<<<dim3(D_INNER / 256, NSEG, BB), 256, 0, stream>>>(
      deltab, ucb, xd, zsb, A_log, Dvec, aprod, ucb);

  // 7. out_proj + residual (BN=64 -> 512 blocks)
  gemm_bf16_kernel<2, 2, float><<<dim3(16, 32), 256, 0, stream>>>(
      ucb, D_INNER, wop, D_INNER, out, D_MODEL, TT, D_MODEL, D_INNER,
      nullptr, x, D_MODEL, nullptr, 1);
}

// Round 7
// 336.930 us; speedup vs baseline: 9.9048x; 1.0770x over previous
//
#include <hip/hip_runtime.h>
#include <hip/hip_bf16.h>
#include <cstddef>

#define D_MODEL 1024
#define D_STATE 16
#define D_CONV 4
#define DT_RANK 64
#define D_INNER 2048
#define BB 2
#define LL 2048
#define TT (BB * LL)          // 4096 tokens
#define NSEG 64
#define SEGLEN (LL / NSEG)    // 32
#define NCHAN (BB * D_INNER)  // 4096

typedef __bf16 bf16x8 __attribute__((ext_vector_type(8)));
typedef float floatx4 __attribute__((ext_vector_type(4)));
typedef unsigned short ushortx8 __attribute__((ext_vector_type(8)));

__device__ __forceinline__ unsigned short f2bf(float f) {
  unsigned u = __float_as_uint(f);
  unsigned r = u + 0x7FFF + ((u >> 16) & 1);  // round-to-nearest-even
  return (unsigned short)(r >> 16);
}
__device__ __forceinline__ float b2f(unsigned short v) {
  return __uint_as_float((unsigned)v << 16);
}

// ---------------------------------------------------------------------------
// prep: blocks [0,TT) = LayerNorm (one token each); remaining blocks do the
// 4 weight casts (contiguous bf16 dst) and zero xd for split-K atomics.
// f4 ranges: in_proj [0,1048576) out_proj [.,1572864) x_proj [.,1622016)
// dt_proj [.,1654784) zero-xd [.,1753088)
// ---------------------------------------------------------------------------
__global__ __launch_bounds__(256) void prep_kernel(
    const float* __restrict__ x, const float* __restrict__ lnw,
    const float* __restrict__ lnb, unsigned short* __restrict__ xnb,
    const float* __restrict__ w0, const float* __restrict__ w1,
    const float* __restrict__ w2, const float* __restrict__ w3,
    unsigned short* __restrict__ wdst, float* __restrict__ xd) {
  const int tid = threadIdx.x;
  if (blockIdx.x < TT) {
    int t = blockIdx.x;
    const float4* xr = reinterpret_cast<const float4*>(x + (size_t)t * D_MODEL);
    float4 xv = xr[tid];
    float s = xv.x + xv.y + xv.z + xv.w;
    float sq = xv.x * xv.x + xv.y * xv.y + xv.z * xv.z + xv.w * xv.w;
    for (int off = 32; off >= 1; off >>= 1) {
      s += __shfl_down(s, off);
      sq += __shfl_down(sq, off);
    }
    __shared__ float red[8];
    int wave = tid >> 6;
    if ((tid & 63) == 0) { red[wave * 2] = s; red[wave * 2 + 1] = sq; }
    __syncthreads();
    if (tid == 0) {
      float S = 0.f, Q = 0.f;
      for (int i = 0; i < 4; ++i) { S += red[2 * i]; Q += red[2 * i + 1]; }
      float mean = S * (1.f / D_MODEL);
      float var = Q * (1.f / D_MODEL) - mean * mean;
      red[0] = mean;
      red[1] = rsqrtf(var + 1e-5f);
    }
    __syncthreads();
    float mean = red[0], inv = red[1];
    float4 wv = reinterpret_cast<const float4*>(lnw)[tid];
    float4 bv = reinterpret_cast<const float4*>(lnb)[tid];
    ushort4 o;
    o.x = f2bf((xv.x - mean) * inv * wv.x + bv.x);
    o.y = f2bf((xv.y - mean) * inv * wv.y + bv.y);
    o.z = f2bf((xv.z - mean) * inv * wv.z + bv.z);
    o.w = f2bf((xv.w - mean) * inv * wv.w + bv.w);
    reinterpret_cast<ushort4*>(xnb + (size_t)t * D_MODEL)[tid] = o;
    return;
  }
  int i = (blockIdx.x - TT) * 256 + tid;
  const float* src;
  int off;
  if (i < 1048576) { src = w0; off = 0; }
  else if (i < 1572864) { src = w1; off = 1048576; }
  else if (i < 1622016) { src = w2; off = 1572864; }
  else if (i < 1654784) { src = w3; off = 1622016; }
  else {
    float4 zz = {0.f, 0.f, 0.f, 0.f};
    reinterpret_cast<float4*>(xd)[i - 1654784] = zz;
    return;
  }
  float4 v = reinterpret_cast<const float4*>(src)[i - off];
  ushort4 o;
  o.x = f2bf(v.x); o.y = f2bf(v.y); o.z = f2bf(v.z); o.w = f2bf(v.w);
  reinterpret_cast<ushort4*>(wdst)[i] = o;
}

// ---------------------------------------------------------------------------
// bf16 MFMA NT GEMM: C[M,N] = A[M,K] * B[N,K]^T. BM=128, BN=WNF*32, BK=64.
// LDS <= 32KB always (epilogue staging in two 32-row rounds, overlaying tile).
// AF32: A is fp32 (lda in floats), converted to bf16 during LDS staging
//       (used by dt_proj reading xd directly; requires K == 64).
// XCD-band swizzle for L2 locality. kslice>1: K-sliced atomic f32 accumulate.
// EPI 0: f32 (atomic if kslice>1); 1: softplus(v+bias[col]) -> bf16;
// EPI 2: v+resid -> f32; 4: in_proj dual bf16 (u plain / silu -> C2).
// ---------------------------------------------------------------------------
template <int WNF, int EPI, bool AF32, typename OT>
__global__ __launch_bounds__(256) void gemm_bf16_kernel(
    const void* __restrict__ Ap, int lda,
    const unsigned short* __restrict__ B, int ldb,
    OT* __restrict__ C, int ldc, int M, int N, int K,
    const float* __restrict__ bias, const float* __restrict__ resid, int ldr,
    unsigned short* __restrict__ C2, int kslice) {
  constexpr int BN = WNF * 32;
  constexpr int BSLOTS = BN * 8;  // 16B slots in B tile
  constexpr int SMEM_USH = 8192 + BN * 64;  // <= 16384 ush = 32 KB
  __shared__ unsigned short sm[SMEM_USH];
  unsigned short* Atile = sm;
  unsigned short* Btile = sm + 8192;

  const int tid = threadIdx.x;
  const int lane = tid & 63;
  const int wv = tid >> 6;
  const int wrow = (wv >> 1) * 64;
  const int wcol = (wv & 1) * (WNF * 16);
  // XCD-band block swizzle (gy == 32 for all launches)
  int gx = gridDim.x, gy = gridDim.y;
  int lid = blockIdx.y * gx + blockIdx.x;
  int rpx = gy >> 3;
  int xcd = lid & 7;
  int qq0 = lid >> 3;
  int by = xcd * rpx + (qq0 % rpx);
  int bx = qq0 / rpx;
  const int row0 = by * 128;
  const int col0 = bx * BN;
  const int m = lane & 15;
  const int q = lane >> 4;

  int k0lo = 0, k0hi = K;
  if (kslice > 1) {
    int ks = K / kslice;
    k0lo = blockIdx.z * ks;
    k0hi = k0lo + ks;
  }

  floatx4 acc[4][WNF] = {};

  for (int k0 = k0lo; k0 < k0hi; k0 += 64) {
#pragma unroll
    for (int t = 0; t < 4; ++t) {
      int slot = wv * 256 + t * 64 + lane;
      int row = slot >> 3;
      int kg = (slot & 7) ^ (row & 7);
      if (AF32) {
        const float* ga = (const float*)Ap + (size_t)(row0 + row) * lda + k0 + kg * 8;
        float4 v0 = *reinterpret_cast<const float4*>(ga);
        float4 v1 = *reinterpret_cast<const float4*>(ga + 4);
        ushortx8 pk;
        pk[0] = f2bf(v0.x); pk[1] = f2bf(v0.y); pk[2] = f2bf(v0.z); pk[3] = f2bf(v0.w);
        pk[4] = f2bf(v1.x); pk[5] = f2bf(v1.y); pk[6] = f2bf(v1.z); pk[7] = f2bf(v1.w);
        *reinterpret_cast<ushortx8*>(Atile + slot * 8) = pk;
      } else {
        const unsigned short* ga =
            (const unsigned short*)Ap + (size_t)(row0 + row) * lda + k0 + kg * 8;
        __builtin_amdgcn_global_load_lds(
            (const __attribute__((address_space(1))) void*)ga,
            (__attribute__((address_space(3))) void*)(Atile + slot * 8), 16, 0, 0);
      }
    }
#pragma unroll
    for (int t = 0; t < BSLOTS / 256; ++t) {
      int slot = t * 256 + tid;
      int row = slot >> 3;
      int kg = (slot & 7) ^ (row & 7);
      int rowB = col0 + row;
      if (rowB >= N) rowB = N - 1;  // clamp (x_proj N=96)
      const unsigned short* gb = B + (size_t)rowB * ldb + k0 + kg * 8;
      __builtin_amdgcn_global_load_lds(
          (const __attribute__((address_space(1))) void*)gb,
          (__attribute__((address_space(3))) void*)(Btile + slot * 8), 16, 0, 0);
    }
    __syncthreads();
#pragma unroll
    for (int s = 0; s < 2; ++s) {
      int xr = ((s * 4 + q) ^ (m & 7)) * 8;
      bf16x8 af[4], bfr[WNF];
#pragma unroll
      for (int i = 0; i < 4; ++i)
        af[i] = *reinterpret_cast<const bf16x8*>(
            Atile + (wrow + i * 16 + m) * 64 + xr);
#pragma unroll
      for (int j = 0; j < WNF; ++j)
        bfr[j] = *reinterpret_cast<const bf16x8*>(
            Btile + (wcol + j * 16 + m) * 64 + xr);
#pragma unroll
      for (int i = 0; i < 4; ++i)
#pragma unroll
        for (int j = 0; j < WNF; ++j)
          acc[i][j] = __builtin_amdgcn_mfma_f32_16x16x32_bf16(
              af[i], bfr[j], acc[i][j], 0, 0, 0);
    }
    __syncthreads();
  }

  if (EPI == 1 || EPI == 4) {
    // bf16 outputs: pack via LDS in two 32-row rounds (stride 66 breaks bank
    // alignment), then 16B coalesced stores. Stage overlays the tile buffers.
    const bool zhalf = (EPI == 4) && (col0 >= D_INNER);
    unsigned short* Cb;
    int cb;
    if (EPI == 4 && col0 >= D_INNER) { Cb = C2; cb = col0 - D_INNER + wcol; }
    else { Cb = (unsigned short*)C; cb = col0 + wcol; }
    constexpr int LPR = WNF * 2;   // lanes per row (8 ushorts each)
    constexpr int RPI = 64 / LPR;  // rows per store instruction
#pragma unroll
    for (int round = 0; round < 2; ++round) {
      unsigned short* st = sm + wv * 2112;  // 32*66 per wave
      __syncthreads();
#pragma unroll
      for (int ii = 0; ii < 2; ++ii) {
        int i = round * 2 + ii;
#pragma unroll
        for (int j = 0; j < WNF; ++j)
#pragma unroll
          for (int r = 0; r < 4; ++r) {
            float v = acc[i][j][r];
            if (EPI == 1) {
              float xv = v + bias[col0 + wcol + j * 16 + m];
              v = fmaxf(xv, 0.f) + log1pf(expf(-fabsf(xv)));
            } else if (zhalf) {
              v = v / (1.f + expf(-v));
            }
            st[(ii * 16 + q * 4 + r) * 66 + j * 16 + m] = f2bf(v);
          }
      }
      __syncthreads();
#pragma unroll
      for (int t = 0; t < 32 / RPI; ++t) {
        int r = t * RPI + lane / LPR;
        int co = (lane % LPR) * 8;
        ushortx8 val = *reinterpret_cast<const ushortx8*>(st + r * 66 + co);
        *reinterpret_cast<ushortx8*>(
            Cb + (size_t)(row0 + wrow + round * 32 + r) * ldc + cb + co) = val;
      }
    }
  } else {
    // f32 epilogue (EPI 0 / 2); stores are 64B-coalesced per lane quad.
#pragma unroll
    for (int j = 0; j < WNF; ++j) {
      int gc = col0 + wcol + j * 16 + m;
      if (gc >= N) continue;
#pragma unroll
      for (int i = 0; i < 4; ++i) {
#pragma unroll
        for (int r = 0; r < 4; ++r) {
          int gr = row0 + wrow + i * 16 + q * 4 + r;
          float v = acc[i][j][r];
          if (EPI == 2) {
            ((float*)C)[(size_t)gr * ldc + gc] = v + resid[(size_t)gr * ldr + gc];
          } else {
            if (kslice > 1)
              atomicAdd(&((float*)C)[(size_t)gr * ldc + gc], v);
            else
              ((float*)C)[(size_t)gr * ldc + gc] = v;
          }
        }
      }
    }
  }
}

// ---------------------------------------------------------------------------
// Depthwise causal conv (width 4) + SiLU; bf16 in/out, 8 channels per thread.
// ---------------------------------------------------------------------------
__global__ __launch_bounds__(256) void conv_silu_kernel(
    const unsigned short* __restrict__ ub, const float* __restrict__ cw,
    const float* __restrict__ cb, unsigned short* __restrict__ ucb) {
  size_t i8 = ((size_t)blockIdx.x * 256 + threadIdx.x) * 8;
  if (i8 >= (size_t)TT * D_INNER) return;
  int d0 = (int)(i8 & (D_INNER - 1));
  int t = (int)(i8 >> 11);
  int l = t & (LL - 1);
  ushortx8 rows[D_CONV];
#pragma unroll
  for (int k = 0; k < D_CONV; ++k) {
    int ll = l - (D_CONV - 1) + k;
    if (ll >= 0)
      rows[k] = *reinterpret_cast<const ushortx8*>(
          ub + i8 - (size_t)(D_CONV - 1 - k) * D_INNER);
    else
      rows[k] = ushortx8{0, 0, 0, 0, 0, 0, 0, 0};
  }
  ushortx8 o;
#pragma unroll
  for (int j = 0; j < 8; ++j) {
    int d = d0 + j;
    float acc = cb[d];
#pragma unroll
    for (int k = 0; k < D_CONV; ++k)
      acc += b2f(rows[k][j]) * cw[d * D_CONV + k];
    o[j] = f2bf(acc / (1.f + expf(-acc)));
  }
  *reinterpret_cast<ushortx8*>(ucb + i8) = o;
}

// ---------------------------------------------------------------------------
// Segmented selective scan, channel-per-thread (h[16] in VGPRs). delta bf16.
// ---------------------------------------------------------------------------
__global__ __launch_bounds__(256) void scan_partial_kernel(
    const unsigned short* __restrict__ deltab, const unsigned short* __restrict__ ucb,
    const float* __restrict__ xd, const float* __restrict__ A_log,
    float* __restrict__ aprod_buf, float* __restrict__ hend_buf) {
  __shared__ float Bs[SEGLEN][16];
  const int tid = threadIdx.x;
  const int d = blockIdx.x * 256 + tid;
  const int s = blockIdx.y;
  const int b = blockIdx.z;
  const int chan = b * D_INNER + d;
  const size_t tbase = (size_t)b * LL + (size_t)s * SEGLEN;

  {
    int row = tid >> 3, pair = tid & 7;
    *reinterpret_cast<float2*>(&Bs[row][pair * 2]) =
        *reinterpret_cast<const float2*>(xd + (tbase + row) * 96 + 64 + pair * 2);
  }
  floatx4 Ac[4];
  {
    const floatx4* ar = reinterpret_cast<const floatx4*>(A_log + (size_t)d * D_STATE);
#pragma unroll
    for (int k = 0; k < 4; ++k) {
      floatx4 v = ar[k];
      for (int j = 0; j < 4; ++j) Ac[k][j] = -__expf(v[j]) * 1.4426950408889634f;
    }
  }
  __syncthreads();

  floatx4 h[4] = {};
  float S = 0.f;
  for (int l = 0; l < SEGLEN; ++l) {
    size_t t = tbase + l;
    float dl = b2f(deltab[t * D_INNER + d]);
    float ul = b2f(ucb[t * D_INNER + d]);
    float dlul = dl * ul;
    S += dl;
#pragma unroll
    for (int k = 0; k < 4; ++k) {
      floatx4 bv = *reinterpret_cast<const floatx4*>(&Bs[l][k * 4]);
      floatx4 a;
      for (int j = 0; j < 4; ++j) a[j] = __builtin_amdgcn_exp2f(dl * Ac[k][j]);
      h[k] = a * h[k] + dlul * bv;
    }
  }
  size_t base = ((size_t)s * NCHAN + chan) * D_STATE;
#pragma unroll
  for (int k = 0; k < 4; ++k) {
    floatx4 ap;
    for (int j = 0; j < 4; ++j) ap[j] = __builtin_amdgcn_exp2f(S * Ac[k][j]);
    *reinterpret_cast<floatx4*>(hend_buf + base + k * 4) = h[k];
    *reinterpret_cast<floatx4*>(aprod_buf + base + k * 4) = ap;
  }
}

__global__ __launch_bounds__(256) void scan_combine_kernel(
    float* __restrict__ aprod_buf, const float* __restrict__ hend_buf) {
  int idx = blockIdx.x * 256 + threadIdx.x;  // chan*16 + n, 65536 total
  float H = 0.f;
  for (int s = 0; s < NSEG; ++s) {
    size_t si = (size_t)s * (NCHAN * D_STATE) + idx;
    float a = aprod_buf[si];
    float he = hend_buf[si];
    aprod_buf[si] = H;  // h_start for segment s
    H = he + a * H;
  }
}

__global__ __launch_bounds__(256) void scan_final_kernel(
    const unsigned short* __restrict__ deltab, const unsigned short* __restrict__ ucb,
    const float* __restrict__ xd, const unsigned short* __restrict__ zsb,
    const float* __restrict__ A_log, const float* __restrict__ Dv,
    const float* __restrict__ hstart_buf, unsigned short* __restrict__ yb) {
  __shared__ float BCs[SEGLEN][32];
  const int tid = threadIdx.x;
  const int d = blockIdx.x * 256 + tid;
  const int s = blockIdx.y;
  const int b = blockIdx.z;
  const int chan = b * D_INNER + d;
  const size_t tbase = (size_t)b * LL + (size_t)s * SEGLEN;

  {
    int row = tid >> 3, quad = tid & 7;
    *reinterpret_cast<float4*>(&BCs[row][quad * 4]) =
        *reinterpret_cast<const float4*>(xd + (tbase + row) * 96 + 64 + quad * 4);
  }
  floatx4 Ac[4];
  {
    const floatx4* ar = reinterpret_cast<const floatx4*>(A_log + (size_t)d * D_STATE);
#pragma unroll
    for (int k = 0; k < 4; ++k) {
      floatx4 v = ar[k];
      for (int j = 0; j < 4; ++j) Ac[k][j] = -__expf(v[j]) * 1.4426950408889634f;
    }
  }
  float Dd = Dv[d];
  floatx4 h[4];
  {
    size_t base = ((size_t)s * NCHAN + chan) * D_STATE;
#pragma unroll
    for (int k = 0; k < 4; ++k)
      h[k] = *reinterpret_cast<const floatx4*>(hstart_buf + base + k * 4);
  }
  __syncthreads();

  for (int l = 0; l < SEGLEN; ++l) {
    size_t t = tbase + l;
    float dl = b2f(deltab[t * D_INNER + d]);
    float ul = b2f(ucb[t * D_INNER + d]);
    float dlul = dl * ul;
    floatx4 psum = {};
#pragma unroll
    for (int k = 0; k < 4; ++k) {
      floatx4 bv = *reinterpret_cast<const floatx4*>(&BCs[l][k * 4]);
      floatx4 cv = *reinterpret_cast<const floatx4*>(&BCs[l][16 + k * 4]);
      floatx4 a;
      for (int j = 0; j < 4; ++j) a[j] = __builtin_amdgcn_exp2f(dl * Ac[k][j]);
      h[k] = a * h[k] + dlul * bv;
      psum += h[k] * cv;
    }
    float p = psum[0] + psum[1] + psum[2] + psum[3];
    float zs = b2f(zsb[t * D_INNER + d]);
    yb[t * D_INNER + d] = f2bf((p + ul * Dd) * zs);  // in-place over ucb: safe
  }
}

// ---------------------------------------------------------------------------
extern "C" void kernel_launch(void* const* d_in, const int* in_sizes, int n_in,
                              void* d_out, int out_size, void* d_ws, size_t ws_size,
                              hipStream_t stream) {
  const float* x         = (const float*)d_in[0];
  const float* ln_w      = (const float*)d_in[1];
  const float* ln_b      = (const float*)d_in[2];
  const float* in_proj_w = (const float*)d_in[3];
  const float* conv_w    = (const float*)d_in[4];
  const float* conv_b    = (const float*)d_in[5];
  const float* x_proj_w  = (const float*)d_in[6];
  const float* dt_proj_w = (const float*)d_in[7];
  const float* dt_proj_b = (const float*)d_in[8];
  const float* A_log     = (const float*)d_in[9];
  const float* Dvec      = (const float*)d_in[10];
  const float* out_proj_w= (const float*)d_in[11];
  float* out = (float*)d_out;

  // workspace layout (all segment sizes multiples of 8 ushorts -> 16B aligned)
  unsigned short* wip = (unsigned short*)d_ws;            // 4194304
  unsigned short* wop = wip + 4194304;                    // 2097152
  unsigned short* wxp = wop + 2097152;                    // 196608
  unsigned short* wdt = wxp + 196608;                     // 131072
  unsigned short* xnb = wdt + 131072;                     // T*1024
  unsigned short* ub  = xnb + (size_t)TT * D_MODEL;       // T*2048 (u bf16)
  unsigned short* ucb = ub + (size_t)TT * D_INNER;        // T*2048 (conv out -> y)
  unsigned short* zsb = ucb + (size_t)TT * D_INNER;       // T*2048 (silu(z))
  unsigned short* deltab = zsb + (size_t)TT * D_INNER;    // T*2048 (delta bf16)
  float* xd    = (float*)(deltab + (size_t)TT * D_INNER); // T*96 f32
  float* hend  = xd + (size_t)TT * 96;                    // NSEG*NCHAN*16
  float* aprod = hend + (size_t)NSEG * NCHAN * D_STATE;   // NSEG*NCHAN*16

  // 0. LayerNorm + weight casts + xd zeroing, one launch
  prep_kernel<<<TT + 6848, 256, 0, stream>>>(x, ln_w, ln_b, xnb, in_proj_w,
                                             out_proj_w, x_proj_w, dt_proj_w,
                                             wip, xd);

  // 1. fused in_proj -> u bf16 (cols<2048), silu(z) bf16 (cols>=2048)
  gemm_bf16_kernel<4, 4, false, unsigned short><<<dim3(32, 32), 256, 0, stream>>>(
      xnb, D_MODEL, wip, D_MODEL, ub, D_INNER, TT, 2 * D_INNER, D_MODEL,
      nullptr, nullptr, 0, zsb, 1);

  // 2. causal depthwise conv + SiLU -> bf16 (8 channels/thread)
  conv_silu_kernel<<<(TT * D_INNER) / (256 * 8), 256, 0, stream>>>(
      ub, conv_w, conv_b, ucb);

  // 3. x_proj -> xd f32 (N=96), BN=64, split-K=4 with atomics
  gemm_bf16_kernel<2, 0, false, float><<<dim3(2, 32, 4), 256, 0, stream>>>(
      ucb, D_INNER, wxp, D_INNER, xd, 96, TT, 96, D_INNER,
      nullptr, nullptr, 0, nullptr, 4);

  // 4. dt_proj (A staged straight from f32 xd) + softplus -> delta bf16
  gemm_bf16_kernel<4, 1, true, unsigned short><<<dim3(16, 32), 256, 0, stream>>>(
      xd, 96, wdt, DT_RANK, deltab, D_INNER, TT, D_INNER, DT_RANK,
      dt_proj_b, nullptr, 0, nullptr, 1);

  // 5. segmented selective scan + gate -> y bf16 (in ucb)
  scan_partial_kernel<<<dim3(D_INNER / 256, NSEG, BB), 256, 0, stream>>>(
      deltab, ucb, xd, A_log, aprod, hend);
  scan_combine_kernel<<<(NCHAN * D_STATE) / 256, 256, 0, stream>>>(aprod, hend);
  scan_final_kernel<<<dim3(D_INNER / 256, NSEG, BB), 256, 0, stream>>>(
      deltab, ucb, xd, zsb, A_log, Dvec, aprod, ucb);

  // 6. out_proj + residual (BN=64 -> 512 blocks)
  gemm_bf16_kernel<2, 2, false, float><<<dim3(16, 32), 256, 0, stream>>>(
      ucb, D_INNER, wop, D_INNER, out, D_MODEL, TT, D_MODEL, D_INNER,
      nullptr, x, D_MODEL, nullptr, 1);
}

// Round 8
// 325.615 us; speedup vs baseline: 10.2490x; 1.0347x over previous
//
#include <hip/hip_runtime.h>
#include <hip/hip_bf16.h>
#include <cstddef>

#define D_MODEL 1024
#define D_STATE 16
#define D_CONV 4
#define DT_RANK 64
#define D_INNER 2048
#define BB 2
#define LL 2048
#define TT (BB * LL)          // 4096 tokens
#define NSEG 64
#define SEGLEN (LL / NSEG)    // 32
#define NCHAN (BB * D_INNER)  // 4096

typedef __bf16 bf16x8 __attribute__((ext_vector_type(8)));
typedef float floatx4 __attribute__((ext_vector_type(4)));
typedef unsigned short ushortx8 __attribute__((ext_vector_type(8)));

__device__ __forceinline__ unsigned short f2bf(float f) {
  unsigned u = __float_as_uint(f);
  unsigned r = u + 0x7FFF + ((u >> 16) & 1);  // round-to-nearest-even
  return (unsigned short)(r >> 16);
}
__device__ __forceinline__ float b2f(unsigned short v) {
  return __uint_as_float((unsigned)v << 16);
}

// ---------------------------------------------------------------------------
// prep: blocks [0,TT) = LayerNorm; rest = weight casts + xd zeroing.
// ---------------------------------------------------------------------------
__global__ __launch_bounds__(256) void prep_kernel(
    const float* __restrict__ x, const float* __restrict__ lnw,
    const float* __restrict__ lnb, unsigned short* __restrict__ xnb,
    const float* __restrict__ w0, const float* __restrict__ w1,
    const float* __restrict__ w2, const float* __restrict__ w3,
    unsigned short* __restrict__ wdst, float* __restrict__ xd) {
  const int tid = threadIdx.x;
  if (blockIdx.x < TT) {
    int t = blockIdx.x;
    const float4* xr = reinterpret_cast<const float4*>(x + (size_t)t * D_MODEL);
    float4 xv = xr[tid];
    float s = xv.x + xv.y + xv.z + xv.w;
    float sq = xv.x * xv.x + xv.y * xv.y + xv.z * xv.z + xv.w * xv.w;
    for (int off = 32; off >= 1; off >>= 1) {
      s += __shfl_down(s, off);
      sq += __shfl_down(sq, off);
    }
    __shared__ float red[8];
    int wave = tid >> 6;
    if ((tid & 63) == 0) { red[wave * 2] = s; red[wave * 2 + 1] = sq; }
    __syncthreads();
    if (tid == 0) {
      float S = 0.f, Q = 0.f;
      for (int i = 0; i < 4; ++i) { S += red[2 * i]; Q += red[2 * i + 1]; }
      float mean = S * (1.f / D_MODEL);
      float var = Q * (1.f / D_MODEL) - mean * mean;
      red[0] = mean;
      red[1] = rsqrtf(var + 1e-5f);
    }
    __syncthreads();
    float mean = red[0], inv = red[1];
    float4 wv = reinterpret_cast<const float4*>(lnw)[tid];
    float4 bv = reinterpret_cast<const float4*>(lnb)[tid];
    ushort4 o;
    o.x = f2bf((xv.x - mean) * inv * wv.x + bv.x);
    o.y = f2bf((xv.y - mean) * inv * wv.y + bv.y);
    o.z = f2bf((xv.z - mean) * inv * wv.z + bv.z);
    o.w = f2bf((xv.w - mean) * inv * wv.w + bv.w);
    reinterpret_cast<ushort4*>(xnb + (size_t)t * D_MODEL)[tid] = o;
    return;
  }
  int i = (blockIdx.x - TT) * 256 + tid;
  const float* src;
  int off;
  if (i < 1048576) { src = w0; off = 0; }
  else if (i < 1572864) { src = w1; off = 1048576; }
  else if (i < 1622016) { src = w2; off = 1572864; }
  else if (i < 1654784) { src = w3; off = 1622016; }
  else {
    float4 zz = {0.f, 0.f, 0.f, 0.f};
    reinterpret_cast<float4*>(xd)[i - 1654784] = zz;
    return;
  }
  float4 v = reinterpret_cast<const float4*>(src)[i - off];
  ushort4 o;
  o.x = f2bf(v.x); o.y = f2bf(v.y); o.z = f2bf(v.z); o.w = f2bf(v.w);
  reinterpret_cast<ushort4*>(wdst)[i] = o;
}

// ---------------------------------------------------------------------------
// bf16 MFMA NT GEMM. BM=128, BN=WNF*32, BK=64, LDS <= 32 KB.
// CLAMP: clamp B rows to N-1 (only x_proj needs it).
// EPI 0: f32 (atomic if kslice>1); 2: v+resid f32; 4: in_proj dual bf16.
// ---------------------------------------------------------------------------
template <int WNF, int EPI, bool CLAMP, typename OT>
__global__ __launch_bounds__(256) void gemm_bf16_kernel(
    const unsigned short* __restrict__ A, int lda,
    const unsigned short* __restrict__ B, int ldb,
    OT* __restrict__ C, int ldc, int M, int N, int K,
    const float* __restrict__ bias, const float* __restrict__ resid, int ldr,
    unsigned short* __restrict__ C2, int kslice) {
  constexpr int BN = WNF * 32;
  constexpr int BSLOTS = BN * 8;
  constexpr int SMEM_USH = 8192 + BN * 64;
  __shared__ unsigned short sm[SMEM_USH];
  unsigned short* Atile = sm;
  unsigned short* Btile = sm + 8192;

  const int tid = threadIdx.x;
  const int lane = tid & 63;
  const int wv = tid >> 6;
  const int wrow = (wv >> 1) * 64;
  const int wcol = (wv & 1) * (WNF * 16);
  int gx = gridDim.x, gy = gridDim.y;
  int lid = blockIdx.y * gx + blockIdx.x;
  int rpx = gy >> 3;
  int xcd = lid & 7;
  int qq0 = lid >> 3;
  int by = xcd * rpx + (qq0 % rpx);
  int bx = qq0 / rpx;
  const int row0 = by * 128;
  const int col0 = bx * BN;
  const int m = lane & 15;
  const int q = lane >> 4;

  int k0lo = 0, k0hi = K;
  if (kslice > 1) {
    int ks = K / kslice;
    k0lo = blockIdx.z * ks;
    k0hi = k0lo + ks;
  }

  floatx4 acc[4][WNF] = {};

  for (int k0 = k0lo; k0 < k0hi; k0 += 64) {
#pragma unroll
    for (int t = 0; t < 4; ++t) {
      int slot = wv * 256 + t * 64 + lane;
      int row = slot >> 3;
      int kg = (slot & 7) ^ (row & 7);
      const unsigned short* ga = A + (size_t)(row0 + row) * lda + k0 + kg * 8;
      __builtin_amdgcn_global_load_lds(
          (const __attribute__((address_space(1))) void*)ga,
          (__attribute__((address_space(3))) void*)(Atile + slot * 8), 16, 0, 0);
    }
#pragma unroll
    for (int t = 0; t < BSLOTS / 256; ++t) {
      int slot = t * 256 + tid;
      int row = slot >> 3;
      int kg = (slot & 7) ^ (row & 7);
      int rowB = col0 + row;
      if (CLAMP && rowB >= N) rowB = N - 1;
      const unsigned short* gb = B + (size_t)rowB * ldb + k0 + kg * 8;
      __builtin_amdgcn_global_load_lds(
          (const __attribute__((address_space(1))) void*)gb,
          (__attribute__((address_space(3))) void*)(Btile + slot * 8), 16, 0, 0);
    }
    __syncthreads();
#pragma unroll
    for (int s = 0; s < 2; ++s) {
      int xr = ((s * 4 + q) ^ (m & 7)) * 8;
      bf16x8 af[4], bfr[WNF];
#pragma unroll
      for (int i = 0; i < 4; ++i)
        af[i] = *reinterpret_cast<const bf16x8*>(
            Atile + (wrow + i * 16 + m) * 64 + xr);
#pragma unroll
      for (int j = 0; j < WNF; ++j)
        bfr[j] = *reinterpret_cast<const bf16x8*>(
            Btile + (wcol + j * 16 + m) * 64 + xr);
#pragma unroll
      for (int i = 0; i < 4; ++i)
#pragma unroll
        for (int j = 0; j < WNF; ++j)
          acc[i][j] = __builtin_amdgcn_mfma_f32_16x16x32_bf16(
              af[i], bfr[j], acc[i][j], 0, 0, 0);
    }
    __syncthreads();
  }

  if (EPI == 4) {
    // bf16 outputs via LDS in two 32-row rounds, then 16B coalesced stores.
    const bool zhalf = (col0 >= D_INNER);
    unsigned short* Cb;
    int cb;
    if (zhalf) { Cb = C2; cb = col0 - D_INNER + wcol; }
    else { Cb = (unsigned short*)C; cb = col0 + wcol; }
    constexpr int LPR = WNF * 2;
    constexpr int RPI = 64 / LPR;
#pragma unroll
    for (int round = 0; round < 2; ++round) {
      unsigned short* st = sm + wv * 2112;
      __syncthreads();
#pragma unroll
      for (int ii = 0; ii < 2; ++ii) {
        int i = round * 2 + ii;
#pragma unroll
        for (int j = 0; j < WNF; ++j)
#pragma unroll
          for (int r = 0; r < 4; ++r) {
            float v = acc[i][j][r];
            if (zhalf) v = v / (1.f + expf(-v));
            st[(ii * 16 + q * 4 + r) * 66 + j * 16 + m] = f2bf(v);
          }
      }
      __syncthreads();
#pragma unroll
      for (int t = 0; t < 32 / RPI; ++t) {
        int r = t * RPI + lane / LPR;
        int co = (lane % LPR) * 8;
        ushortx8 val = *reinterpret_cast<const ushortx8*>(st + r * 66 + co);
        *reinterpret_cast<ushortx8*>(
            Cb + (size_t)(row0 + wrow + round * 32 + r) * ldc + cb + co) = val;
      }
    }
  } else {
#pragma unroll
    for (int j = 0; j < WNF; ++j) {
      int gc = col0 + wcol + j * 16 + m;
      if (CLAMP && gc >= N) continue;
#pragma unroll
      for (int i = 0; i < 4; ++i) {
#pragma unroll
        for (int r = 0; r < 4; ++r) {
          int gr = row0 + wrow + i * 16 + q * 4 + r;
          float v = acc[i][j][r];
          if (EPI == 2) {
            ((float*)C)[(size_t)gr * ldc + gc] = v + resid[(size_t)gr * ldr + gc];
          } else {
            if (kslice > 1)
              atomicAdd(&((float*)C)[(size_t)gr * ldc + gc], v);
            else
              ((float*)C)[(size_t)gr * ldc + gc] = v;
          }
        }
      }
    }
  }
}

// ---------------------------------------------------------------------------
// dtscan: dt_proj GEMM (K=64, one BK iteration) + softplus -> delta bf16
// (global, for scan_final) + partial scan phase, all in one kernel.
// Block = 128 tokens (row0) x 128 channels (col0). Threads: ch = t&127,
// segment-pair = t>>7 (each handles 2 of the tile's 4 segments).
// LDS: Atile(8192u) + Btile(8192u) for GEMM, then overlaid delta tile
// st[128][130] + Bf[128][16] f32 (41472 B total).
// ---------------------------------------------------------------------------
__global__ __launch_bounds__(256) void dtscan_kernel(
    const float* __restrict__ xd, const unsigned short* __restrict__ wdt,
    const float* __restrict__ dtb, const unsigned short* __restrict__ ucb,
    const float* __restrict__ A_log, unsigned short* __restrict__ deltab,
    float* __restrict__ aprod_buf, float* __restrict__ hend_buf) {
  __shared__ unsigned short sm[20736];  // 41472 B
  unsigned short* Atile = sm;
  unsigned short* Btile = sm + 8192;

  const int tid = threadIdx.x;
  const int lane = tid & 63;
  const int wv = tid >> 6;
  const int wrow = (wv >> 1) * 64;
  const int wcol = (wv & 1) * 64;
  int gx = gridDim.x, gy = gridDim.y;
  int lid = blockIdx.y * gx + blockIdx.x;
  int rpx = gy >> 3;
  int xcd = lid & 7;
  int qq0 = lid >> 3;
  int by = xcd * rpx + (qq0 % rpx);
  int bx = qq0 / rpx;
  const int row0 = by * 128;
  const int col0 = bx * 128;
  const int m = lane & 15;
  const int q = lane >> 4;

  // --- GEMM: A = xd (f32, lda=96, K=64) staged+converted; B = wdt ---
#pragma unroll
  for (int t = 0; t < 4; ++t) {
    int slot = wv * 256 + t * 64 + lane;
    int row = slot >> 3;
    int kg = (slot & 7) ^ (row & 7);
    const float* ga = xd + (size_t)(row0 + row) * 96 + kg * 8;
    float4 v0 = *reinterpret_cast<const float4*>(ga);
    float4 v1 = *reinterpret_cast<const float4*>(ga + 4);
    ushortx8 pk;
    pk[0] = f2bf(v0.x); pk[1] = f2bf(v0.y); pk[2] = f2bf(v0.z); pk[3] = f2bf(v0.w);
    pk[4] = f2bf(v1.x); pk[5] = f2bf(v1.y); pk[6] = f2bf(v1.z); pk[7] = f2bf(v1.w);
    *reinterpret_cast<ushortx8*>(Atile + slot * 8) = pk;
  }
#pragma unroll
  for (int t = 0; t < 4; ++t) {
    int slot = t * 256 + tid;
    int row = slot >> 3;
    int kg = (slot & 7) ^ (row & 7);
    const unsigned short* gb = wdt + (size_t)(col0 + row) * DT_RANK + kg * 8;
    __builtin_amdgcn_global_load_lds(
        (const __attribute__((address_space(1))) void*)gb,
        (__attribute__((address_space(3))) void*)(Btile + slot * 8), 16, 0, 0);
  }
  __syncthreads();
  floatx4 acc[4][4] = {};
#pragma unroll
  for (int s = 0; s < 2; ++s) {
    int xr = ((s * 4 + q) ^ (m & 7)) * 8;
    bf16x8 af[4], bfr[4];
#pragma unroll
    for (int i = 0; i < 4; ++i)
      af[i] = *reinterpret_cast<const bf16x8*>(Atile + (wrow + i * 16 + m) * 64 + xr);
#pragma unroll
    for (int j = 0; j < 4; ++j)
      bfr[j] = *reinterpret_cast<const bf16x8*>(Btile + (wcol + j * 16 + m) * 64 + xr);
#pragma unroll
    for (int i = 0; i < 4; ++i)
#pragma unroll
      for (int j = 0; j < 4; ++j)
        acc[i][j] = __builtin_amdgcn_mfma_f32_16x16x32_bf16(
            af[i], bfr[j], acc[i][j], 0, 0, 0);
  }
  __syncthreads();  // all LDS reads done; overlay st/Bf

  // --- softplus(acc + bias) -> st[128][130] (bf16) ---
  unsigned short* st = sm;                 // 128*130 ush = 16640
  float* Bf = (float*)(sm + 16640);        // 128*16 f32 = 8192 B
  float bj[4];
#pragma unroll
  for (int j = 0; j < 4; ++j) bj[j] = dtb[col0 + wcol + j * 16 + m];
#pragma unroll
  for (int i = 0; i < 4; ++i)
#pragma unroll
    for (int j = 0; j < 4; ++j)
#pragma unroll
      for (int r = 0; r < 4; ++r) {
        float xv = acc[i][j][r] + bj[j];
        float sp = fmaxf(xv, 0.f) + log1pf(expf(-fabsf(xv)));
        int lrow = wrow + i * 16 + q * 4 + r;
        int lcol = wcol + j * 16 + m;
        st[lrow * 130 + lcol] = f2bf(sp);
      }
  // --- stage B-values (xd cols 64..79) for the scan phase ---
#pragma unroll
  for (int e = 0; e < 2; ++e) {
    int f4 = e * 256 + tid;  // 512 float4 total
    int row = f4 >> 2, part = f4 & 3;
    float4 v = *reinterpret_cast<const float4*>(
        xd + (size_t)(row0 + row) * 96 + 64 + part * 4);
    *reinterpret_cast<float4*>(Bf + row * 16 + part * 4) = v;
  }
  __syncthreads();

  // --- global delta store (coalesced 16B) ---
#pragma unroll
  for (int e = 0; e < 8; ++e) {
    int c = e * 256 + tid;  // 2048 chunks
    int rrow = c >> 4, co = (c & 15) * 8;
    ushortx8 val = *reinterpret_cast<const ushortx8*>(st + rrow * 130 + co);
    *reinterpret_cast<ushortx8*>(
        deltab + (size_t)(row0 + rrow) * D_INNER + col0 + co) = val;
  }

  // --- partial scan phase ---
  const int ch = tid & 127;
  const int sp = tid >> 7;
  const int d = col0 + ch;
  const int b = row0 >> 11;
  const int chan = b * D_INNER + d;
  floatx4 Ac[4];
  {
    const floatx4* ar = reinterpret_cast<const floatx4*>(A_log + (size_t)d * D_STATE);
#pragma unroll
    for (int k = 0; k < 4; ++k) {
      floatx4 v = ar[k];
      for (int j = 0; j < 4; ++j) Ac[k][j] = -__expf(v[j]) * 1.4426950408889634f;
    }
  }
#pragma unroll
  for (int ss = 0; ss < 2; ++ss) {
    int lbase = sp * 64 + ss * 32;
    int seg = ((row0 & (LL - 1)) >> 5) + sp * 2 + ss;
    floatx4 h[4] = {};
    float S = 0.f;
    for (int l = 0; l < SEGLEN; ++l) {
      int lr = lbase + l;
      float dl = b2f(st[lr * 130 + ch]);
      float ul = b2f(ucb[(size_t)(row0 + lr) * D_INNER + d]);
      float dlul = dl * ul;
      S += dl;
#pragma unroll
      for (int k = 0; k < 4; ++k) {
        floatx4 bv = *reinterpret_cast<const floatx4*>(Bf + lr * 16 + k * 4);
        floatx4 a;
        for (int j = 0; j < 4; ++j) a[j] = __builtin_amdgcn_exp2f(dl * Ac[k][j]);
        h[k] = a * h[k] + dlul * bv;
      }
    }
    size_t base = ((size_t)seg * NCHAN + chan) * D_STATE;
#pragma unroll
    for (int k = 0; k < 4; ++k) {
      floatx4 ap;
      for (int j = 0; j < 4; ++j) ap[j] = __builtin_amdgcn_exp2f(S * Ac[k][j]);
      *reinterpret_cast<floatx4*>(hend_buf + base + k * 4) = h[k];
      *reinterpret_cast<floatx4*>(aprod_buf + base + k * 4) = ap;
    }
  }
}

// ---------------------------------------------------------------------------
// Depthwise causal conv (width 4) + SiLU; bf16 in/out, 8 channels per thread.
// ---------------------------------------------------------------------------
__global__ __launch_bounds__(256) void conv_silu_kernel(
    const unsigned short* __restrict__ ub, const float* __restrict__ cw,
    const float* __restrict__ cb, unsigned short* __restrict__ ucb) {
  size_t i8 = ((size_t)blockIdx.x * 256 + threadIdx.x) * 8;
  if (i8 >= (size_t)TT * D_INNER) return;
  int d0 = (int)(i8 & (D_INNER - 1));
  int t = (int)(i8 >> 11);
  int l = t & (LL - 1);
  ushortx8 rows[D_CONV];
#pragma unroll
  for (int k = 0; k < D_CONV; ++k) {
    int ll = l - (D_CONV - 1) + k;
    if (ll >= 0)
      rows[k] = *reinterpret_cast<const ushortx8*>(
          ub + i8 - (size_t)(D_CONV - 1 - k) * D_INNER);
    else
      rows[k] = ushortx8{0, 0, 0, 0, 0, 0, 0, 0};
  }
  ushortx8 o;
#pragma unroll
  for (int j = 0; j < 8; ++j) {
    int d = d0 + j;
    float acc = cb[d];
#pragma unroll
    for (int k = 0; k < D_CONV; ++k)
      acc += b2f(rows[k][j]) * cw[d * D_CONV + k];
    o[j] = f2bf(acc / (1.f + expf(-acc)));
  }
  *reinterpret_cast<ushortx8*>(ucb + i8) = o;
}

// ---------------------------------------------------------------------------
// combine: serial prefix over segments per (chan, n).
// ---------------------------------------------------------------------------
__global__ __launch_bounds__(256) void scan_combine_kernel(
    float* __restrict__ aprod_buf, const float* __restrict__ hend_buf) {
  int idx = blockIdx.x * 256 + threadIdx.x;
  float H = 0.f;
  for (int s = 0; s < NSEG; ++s) {
    size_t si = (size_t)s * (NCHAN * D_STATE) + idx;
    float a = aprod_buf[si];
    float he = hend_buf[si];
    aprod_buf[si] = H;
    H = he + a * H;
  }
}

__global__ __launch_bounds__(256) void scan_final_kernel(
    const unsigned short* __restrict__ deltab, const unsigned short* __restrict__ ucb,
    const float* __restrict__ xd, const unsigned short* __restrict__ zsb,
    const float* __restrict__ A_log, const float* __restrict__ Dv,
    const float* __restrict__ hstart_buf, unsigned short* __restrict__ yb) {
  __shared__ float BCs[SEGLEN][32];
  const int tid = threadIdx.x;
  const int d = blockIdx.x * 256 + tid;
  const int s = blockIdx.y;
  const int b = blockIdx.z;
  const int chan = b * D_INNER + d;
  const size_t tbase = (size_t)b * LL + (size_t)s * SEGLEN;

  {
    int row = tid >> 3, quad = tid & 7;
    *reinterpret_cast<float4*>(&BCs[row][quad * 4]) =
        *reinterpret_cast<const float4*>(xd + (tbase + row) * 96 + 64 + quad * 4);
  }
  floatx4 Ac[4];
  {
    const floatx4* ar = reinterpret_cast<const floatx4*>(A_log + (size_t)d * D_STATE);
#pragma unroll
    for (int k = 0; k < 4; ++k) {
      floatx4 v = ar[k];
      for (int j = 0; j < 4; ++j) Ac[k][j] = -__expf(v[j]) * 1.4426950408889634f;
    }
  }
  float Dd = Dv[d];
  floatx4 h[4];
  {
    size_t base = ((size_t)s * NCHAN + chan) * D_STATE;
#pragma unroll
    for (int k = 0; k < 4; ++k)
      h[k] = *reinterpret_cast<const floatx4*>(hstart_buf + base + k * 4);
  }
  __syncthreads();

  for (int l = 0; l < SEGLEN; ++l) {
    size_t t = tbase + l;
    float dl = b2f(deltab[t * D_INNER + d]);
    float ul = b2f(ucb[t * D_INNER + d]);
    float dlul = dl * ul;
    floatx4 psum = {};
#pragma unroll
    for (int k = 0; k < 4; ++k) {
      floatx4 bv = *reinterpret_cast<const floatx4*>(&BCs[l][k * 4]);
      floatx4 cv = *reinterpret_cast<const floatx4*>(&BCs[l][16 + k * 4]);
      floatx4 a;
      for (int j = 0; j < 4; ++j) a[j] = __builtin_amdgcn_exp2f(dl * Ac[k][j]);
      h[k] = a * h[k] + dlul * bv;
      psum += h[k] * cv;
    }
    float p = psum[0] + psum[1] + psum[2] + psum[3];
    float zs = b2f(zsb[t * D_INNER + d]);
    yb[t * D_INNER + d] = f2bf((p + ul * Dd) * zs);  // in-place over ucb: safe
  }
}

// ---------------------------------------------------------------------------
extern "C" void kernel_launch(void* const* d_in, const int* in_sizes, int n_in,
                              void* d_out, int out_size, void* d_ws, size_t ws_size,
                              hipStream_t stream) {
  const float* x         = (const float*)d_in[0];
  const float* ln_w      = (const float*)d_in[1];
  const float* ln_b      = (const float*)d_in[2];
  const float* in_proj_w = (const float*)d_in[3];
  const float* conv_w    = (const float*)d_in[4];
  const float* conv_b    = (const float*)d_in[5];
  const float* x_proj_w  = (const float*)d_in[6];
  const float* dt_proj_w = (const float*)d_in[7];
  const float* dt_proj_b = (const float*)d_in[8];
  const float* A_log     = (const float*)d_in[9];
  const float* Dvec      = (const float*)d_in[10];
  const float* out_proj_w= (const float*)d_in[11];
  float* out = (float*)d_out;

  unsigned short* wip = (unsigned short*)d_ws;            // 4194304
  unsigned short* wop = wip + 4194304;                    // 2097152
  unsigned short* wxp = wop + 2097152;                    // 196608
  unsigned short* wdt = wxp + 196608;                     // 131072
  unsigned short* xnb = wdt + 131072;                     // T*1024
  unsigned short* ub  = xnb + (size_t)TT * D_MODEL;       // T*2048 (u bf16)
  unsigned short* ucb = ub + (size_t)TT * D_INNER;        // T*2048 (conv out -> y)
  unsigned short* zsb = ucb + (size_t)TT * D_INNER;       // T*2048 (silu(z))
  unsigned short* deltab = zsb + (size_t)TT * D_INNER;    // T*2048 (delta bf16)
  float* xd    = (float*)(deltab + (size_t)TT * D_INNER); // T*96 f32
  float* hend  = xd + (size_t)TT * 96;                    // NSEG*NCHAN*16
  float* aprod = hend + (size_t)NSEG * NCHAN * D_STATE;   // NSEG*NCHAN*16

  // 0. LayerNorm + weight casts + xd zeroing
  prep_kernel<<<TT + 6848, 256, 0, stream>>>(x, ln_w, ln_b, xnb, in_proj_w,
                                             out_proj_w, x_proj_w, dt_proj_w,
                                             wip, xd);

  // 1. fused in_proj -> u bf16, silu(z) bf16
  gemm_bf16_kernel<4, 4, false, unsigned short><<<dim3(32, 32), 256, 0, stream>>>(
      xnb, D_MODEL, wip, D_MODEL, ub, D_INNER, TT, 2 * D_INNER, D_MODEL,
      nullptr, nullptr, 0, zsb, 1);

  // 2. causal depthwise conv + SiLU -> bf16
  conv_silu_kernel<<<(TT * D_INNER) / (256 * 8), 256, 0, stream>>>(
      ub, conv_w, conv_b, ucb);

  // 3. x_proj -> xd f32 (N=96), BN=64, split-K=4 with atomics
  gemm_bf16_kernel<2, 0, true, float><<<dim3(2, 32, 4), 256, 0, stream>>>(
      ucb, D_INNER, wxp, D_INNER, xd, 96, TT, 96, D_INNER,
      nullptr, nullptr, 0, nullptr, 4);

  // 4. dt_proj + softplus + partial scan, one kernel
  dtscan_kernel<<<dim3(16, 32), 256, 0, stream>>>(
      xd, wdt, dt_proj_b, ucb, A_log, deltab, aprod, hend);

  // 5. combine + final
  scan_combine_kernel<<<(NCHAN * D_STATE) / 256, 256, 0, stream>>>(aprod, hend);
  scan_final_kernel<<<dim3(D_INNER / 256, NSEG, BB), 256, 0, stream>>>(
      deltab, ucb, xd, zsb, A_log, Dvec, aprod, ucb);

  // 6. out_proj + residual
  gemm_bf16_kernel<2, 2, false, float><<<dim3(16, 32), 256, 0, stream>>>(
      ucb, D_INNER, wop, D_INNER, out, D_MODEL, TT, D_MODEL, D_INNER,
      nullptr, x, D_MODEL, nullptr, 1);
}